// Round 2
// baseline (4857.167 us; speedup 1.0000x reference)
//
#include <hip/hip_runtime.h>
#include <hip/hip_bf16.h>

// ---------------------------------------------------------------------------
// ArmNet forward: encoder (3 spatial + temporal) -> transform GEMM -> decoder
// (3 spatial + temporal) -> tanh + affine.  fp32 everywhere except the
// transform output (post-tanh, bounded) which is stored bf16 to fit scratch.
// ---------------------------------------------------------------------------

constexpr int kN1 = 393216;   // encoder nodes
constexpr int kE1 = 327680;   // encoder edges
constexpr int kN2 = 917504;   // decoder nodes
constexpr int kE2 = 851968;   // decoder edges
constexpr int kM  = 65536;    // B*PERIOD (transform GEMM rows)
constexpr int kK  = 384;      // transform K
constexpr int kN  = 896;      // transform N (14*64)

// ---------------- generic spatial edge kernel ------------------------------
// out must be pre-filled with the upsample (residual) term; we atomically add
// the aggregated messages.  z = [x_dst | x_src | ea], m = leaky_relu(Wl z + b).
template<int IN, int EA, int OUT, int TPB>
__global__ __launch_bounds__(TPB)
void spatial_edge_kernel(const float* __restrict__ x,
                         const int* __restrict__ ei, int E,
                         const float* __restrict__ ea,
                         const float* __restrict__ Wl,
                         const float* __restrict__ bl,
                         float* __restrict__ out)
{
    constexpr int Z  = 2 * IN + EA;
    constexpr int Zp = (Z % 2 == 0) ? Z + 1 : Z;   // odd stride: no LDS bank conflicts
    constexpr int EPB = TPB / OUT;
    static_assert(TPB % OUT == 0, "TPB % OUT");
    __shared__ float sW[OUT * Zp];
    __shared__ float sB[OUT];
    for (int i = threadIdx.x; i < OUT * Z; i += TPB)
        sW[(i / Z) * Zp + (i % Z)] = Wl[i];
    for (int i = threadIdx.x; i < OUT; i += TPB) sB[i] = bl[i];
    __syncthreads();

    const int le = threadIdx.x / OUT;
    const int c  = threadIdx.x % OUT;
    const int e  = blockIdx.x * EPB + le;
    if (e >= E) return;
    const int src = ei[e];
    const int dst = ei[E + e];
    const float* __restrict__ w  = &sW[c * Zp];
    const float* __restrict__ xd = &x[(long)dst * IN];
    const float* __restrict__ xs = &x[(long)src * IN];
    float acc = sB[c];
    #pragma unroll
    for (int j = 0; j < IN; ++j) acc = fmaf(w[j], xd[j], acc);
    #pragma unroll
    for (int j = 0; j < IN; ++j) acc = fmaf(w[IN + j], xs[j], acc);
    const float* __restrict__ eav = &ea[(long)e * EA];
    #pragma unroll
    for (int j = 0; j < EA; ++j) acc = fmaf(w[2 * IN + j], eav[j], acc);
    acc = acc > 0.f ? acc : 0.01f * acc;     // leaky_relu(0.01)
    atomicAdd(&out[(long)dst * OUT + c], acc);
}

// ---------------- generic upsample (residual linear) -----------------------
template<int IN, int OUT>
__global__ void upsample_kernel(const float* __restrict__ x, int N,
                                const float* __restrict__ Wu,
                                const float* __restrict__ bu,
                                float* __restrict__ out)
{
    int idx = blockIdx.x * blockDim.x + threadIdx.x;
    if (idx >= N * OUT) return;
    const int n = idx / OUT, c = idx % OUT;
    const float* __restrict__ w  = Wu + c * IN;
    const float* __restrict__ xv = x + (long)n * IN;
    float acc = bu[c];
    #pragma unroll
    for (int j = 0; j < IN; ++j) acc = fmaf(w[j], xv[j], acc);
    out[idx] = acc;
}

// ---------------- decoder layer-1 variants (virtual concat input) ----------
// x2[n, j] = j<64 ? zt[n,j] (bf16) : j==64 ? lower[n] : upper[n]
__global__ __launch_bounds__(256)
void dec1_edge_kernel(const __hip_bfloat16* __restrict__ zt,
                      const float* __restrict__ lo, const float* __restrict__ up,
                      const int* __restrict__ ei, int E,
                      const float* __restrict__ ea,   // EA = 6
                      const float* __restrict__ Wl,   // [32, 138]
                      const float* __restrict__ bl,
                      float* __restrict__ out)        // [N2, 32]
{
    constexpr int OUT = 32, Z = 138, Zp = 139;
    __shared__ float sW[OUT * Zp];
    __shared__ float sB[OUT];
    for (int i = threadIdx.x; i < OUT * Z; i += 256)
        sW[(i / Z) * Zp + (i % Z)] = Wl[i];
    if (threadIdx.x < OUT) sB[threadIdx.x] = bl[threadIdx.x];
    __syncthreads();

    const int le = threadIdx.x >> 5;
    const int c  = threadIdx.x & 31;
    const int e  = blockIdx.x * 8 + le;
    if (e >= E) return;
    const int src = ei[e];
    const int dst = ei[E + e];
    const float* __restrict__ w = &sW[c * Zp];
    const __hip_bfloat16* __restrict__ zd = &zt[(long)dst * 64];
    const __hip_bfloat16* __restrict__ zs = &zt[(long)src * 64];
    float acc = sB[c];
    #pragma unroll
    for (int j = 0; j < 64; ++j) acc = fmaf(w[j], __bfloat162float(zd[j]), acc);
    acc = fmaf(w[64], lo[dst], acc);
    acc = fmaf(w[65], up[dst], acc);
    #pragma unroll
    for (int j = 0; j < 64; ++j) acc = fmaf(w[66 + j], __bfloat162float(zs[j]), acc);
    acc = fmaf(w[130], lo[src], acc);
    acc = fmaf(w[131], up[src], acc);
    const float* __restrict__ eav = &ea[(long)e * 6];
    #pragma unroll
    for (int j = 0; j < 6; ++j) acc = fmaf(w[132 + j], eav[j], acc);
    acc = acc > 0.f ? acc : 0.01f * acc;
    atomicAdd(&out[(long)dst * OUT + c], acc);
}

__global__ void dec1_upsample_kernel(const __hip_bfloat16* __restrict__ zt,
                                     const float* __restrict__ lo,
                                     const float* __restrict__ up,
                                     const float* __restrict__ Wu,  // [32, 66]
                                     const float* __restrict__ bu,
                                     float* __restrict__ out, int N)
{
    int idx = blockIdx.x * blockDim.x + threadIdx.x;
    if (idx >= N * 32) return;
    const int n = idx >> 5, c = idx & 31;
    const float* __restrict__ w = Wu + c * 66;
    const __hip_bfloat16* __restrict__ zn = &zt[(long)n * 64];
    float acc = bu[c];
    #pragma unroll
    for (int j = 0; j < 64; ++j) acc = fmaf(w[j], __bfloat162float(zn[j]), acc);
    acc = fmaf(w[64], lo[n], acc);
    acc = fmaf(w[65], up[n], acc);
    out[idx] = acc;
}

// ---------------- temporal blocks ------------------------------------------
// dim-64 (encoder): m = relu(Wt [x_dst|x_src] + bt), mean-aggregate by dst.
__global__ __launch_bounds__(256)
void temporal_edge64_kernel(const float* __restrict__ x,
                            const int* __restrict__ ei, int E,
                            const float* __restrict__ Wt,  // [64,128]
                            const float* __restrict__ bt,
                            float* __restrict__ s, float* __restrict__ cnt)
{
    __shared__ float sWT[128 * 64];   // transposed: sWT[j*64+c] = Wt[c*128+j]
    __shared__ float sB[64];
    for (int i = threadIdx.x; i < 64 * 128; i += 256) {
        const int c = i >> 7, j = i & 127;
        sWT[j * 64 + c] = Wt[i];
    }
    if (threadIdx.x < 64) sB[threadIdx.x] = bt[threadIdx.x];
    __syncthreads();

    const int le = threadIdx.x >> 6;
    const int c  = threadIdx.x & 63;
    const int e  = blockIdx.x * 4 + le;
    if (e >= E) return;
    const int src = ei[e];
    const int dst = ei[E + e];
    const float* __restrict__ xd = &x[(long)dst * 64];
    const float* __restrict__ xs = &x[(long)src * 64];
    float acc = sB[c];
    #pragma unroll
    for (int j = 0; j < 64; ++j) acc = fmaf(sWT[j * 64 + c], xd[j], acc);
    #pragma unroll
    for (int j = 0; j < 64; ++j) acc = fmaf(sWT[(64 + j) * 64 + c], xs[j], acc);
    acc = fmaxf(acc, 0.f);
    atomicAdd(&s[(long)dst * 64 + c], acc);
    if (c == 0) atomicAdd(&cnt[dst], 1.f);
}

__global__ void temporal_combine64_kernel(const float* __restrict__ s,
                                          const float* __restrict__ cnt,
                                          const float* __restrict__ x,
                                          float* __restrict__ z, int N)
{
    int idx = blockIdx.x * blockDim.x + threadIdx.x;
    if (idx >= N * 64) return;
    const int n = idx >> 6;
    z[idx] = s[idx] / fmaxf(cnt[n], 1.f) + x[idx];
}

// dim-1 (decoder): trivial weights (Wt2 is [1,2]).
__global__ void temporal_edge1_kernel(const float* __restrict__ x,
                                      const int* __restrict__ ei, int E,
                                      const float* __restrict__ Wt,
                                      const float* __restrict__ bt,
                                      float* __restrict__ s, float* __restrict__ cnt)
{
    int e = blockIdx.x * blockDim.x + threadIdx.x;
    if (e >= E) return;
    const int src = ei[e];
    const int dst = ei[E + e];
    float m = Wt[0] * x[dst] + Wt[1] * x[src] + bt[0];
    m = fmaxf(m, 0.f);
    atomicAdd(&s[dst], m);
    atomicAdd(&cnt[dst], 1.f);
}

// ---------------- transform GEMM: [M,384] @ [384,896]^T + bias, tanh -> bf16
__global__ __launch_bounds__(256)
void gemm_tanh_kernel(const float* __restrict__ A,    // [M, 384]
                      const float* __restrict__ W,    // [896, 384]
                      const float* __restrict__ bias, // [896]
                      __hip_bfloat16* __restrict__ out) // [M, 896]
{
    constexpr int BM = 64, BN = 64, BK = 16, LDP = BM + 4;
    __shared__ float As[BK][LDP];
    __shared__ float Bs[BK][LDP];
    const int tid = threadIdx.x;
    const int tx = tid & 15, ty = tid >> 4;
    const int bm = blockIdx.y * BM;
    const int bn = blockIdx.x * BN;
    const int lr = tid >> 2;       // 0..63: tile row to stage
    const int lq = tid & 3;        // which float4 of the 16-wide K slice

    float acc[4][4] = {};
    for (int k0 = 0; k0 < kK; k0 += BK) {
        float4 a4 = *(const float4*)&A[(long)(bm + lr) * kK + k0 + lq * 4];
        float4 b4 = *(const float4*)&W[(long)(bn + lr) * kK + k0 + lq * 4];
        As[lq * 4 + 0][lr] = a4.x; As[lq * 4 + 1][lr] = a4.y;
        As[lq * 4 + 2][lr] = a4.z; As[lq * 4 + 3][lr] = a4.w;
        Bs[lq * 4 + 0][lr] = b4.x; Bs[lq * 4 + 1][lr] = b4.y;
        Bs[lq * 4 + 2][lr] = b4.z; Bs[lq * 4 + 3][lr] = b4.w;
        __syncthreads();
        #pragma unroll
        for (int k = 0; k < BK; ++k) {
            const float4 av = *(const float4*)&As[k][ty * 4];
            const float4 bv = *(const float4*)&Bs[k][tx * 4];
            const float a[4] = {av.x, av.y, av.z, av.w};
            const float b[4] = {bv.x, bv.y, bv.z, bv.w};
            #pragma unroll
            for (int i = 0; i < 4; ++i)
                #pragma unroll
                for (int j = 0; j < 4; ++j)
                    acc[i][j] = fmaf(a[i], b[j], acc[i][j]);
        }
        __syncthreads();
    }
    #pragma unroll
    for (int i = 0; i < 4; ++i) {
        const int row = bm + ty * 4 + i;
        #pragma unroll
        for (int j = 0; j < 4; ++j) {
            const int col = bn + tx * 4 + j;
            const float v = tanhf(acc[i][j] + bias[col]);
            out[(long)row * kN + col] = __float2bfloat16(v);
        }
    }
}

// ---------------- final: tanh(temporal) -> affine to joint range -----------
__global__ void final_kernel(const float* __restrict__ s,
                             const float* __restrict__ cnt,
                             const float* __restrict__ d3,
                             const float* __restrict__ lo,
                             const float* __restrict__ up,
                             float* __restrict__ out, int N)
{
    int i = blockIdx.x * blockDim.x + threadIdx.x;
    if (i >= N) return;
    const float t = s[i] / fmaxf(cnt[i], 1.f) + d3[i];
    const float o = tanhf(t);
    out[i] = lo[i] + (up[i] - lo[i]) * (o + 1.f) * 0.5f;
}

// ---------------------------------------------------------------------------
extern "C" void kernel_launch(void* const* d_in, const int* in_sizes, int n_in,
                              void* d_out, int out_size, void* d_ws, size_t ws_size,
                              hipStream_t stream)
{
    const float* x     = (const float*)d_in[0];
    const int*   ei1   = (const int*)  d_in[1];
    const float* ea1   = (const float*)d_in[2];
    const int*   tei1  = (const int*)  d_in[3];
    const float* lower = (const float*)d_in[4];
    const float* upper = (const float*)d_in[5];
    const int*   ei2   = (const int*)  d_in[6];
    const float* ea2   = (const float*)d_in[7];
    const int*   tei2  = (const int*)  d_in[8];
    const float* We1_l = (const float*)d_in[9];  const float* be1_l = (const float*)d_in[10];
    const float* We1_u = (const float*)d_in[11]; const float* be1_u = (const float*)d_in[12];
    const float* We2_l = (const float*)d_in[13]; const float* be2_l = (const float*)d_in[14];
    const float* We2_u = (const float*)d_in[15]; const float* be2_u = (const float*)d_in[16];
    const float* We3_l = (const float*)d_in[17]; const float* be3_l = (const float*)d_in[18];
    const float* We3_u = (const float*)d_in[19]; const float* be3_u = (const float*)d_in[20];
    const float* Wt1   = (const float*)d_in[21]; const float* bt1   = (const float*)d_in[22];
    const float* W_tr  = (const float*)d_in[23]; const float* b_tr  = (const float*)d_in[24];
    const float* Wd1_l = (const float*)d_in[25]; const float* bd1_l = (const float*)d_in[26];
    const float* Wd1_u = (const float*)d_in[27]; const float* bd1_u = (const float*)d_in[28];
    const float* Wd2_l = (const float*)d_in[29]; const float* bd2_l = (const float*)d_in[30];
    const float* Wd2_u = (const float*)d_in[31]; const float* bd2_u = (const float*)d_in[32];
    const float* Wd3_l = (const float*)d_in[33]; const float* bd3_l = (const float*)d_in[34];
    const float* Wd3_u = (const float*)d_in[35]; const float* bd3_u = (const float*)d_in[36];
    const float* Wt2   = (const float*)d_in[37]; const float* bt2   = (const float*)d_in[38];

    // workspace layout (bytes):
    //   bufA: 117,440,512   (holds h1/h3/zt(bf16)/d2)
    //   bufB: 117,440,512   (holds h2/s1/z/d1/d3)
    //   bufC:   7,340,032   (holds cnt1 | s2+cnt2)
    char* ws = (char*)d_ws;
    float* bufA = (float*)ws;
    float* bufB = (float*)(ws + 117440512);
    float* bufC = (float*)(ws + 234881024);
    __hip_bfloat16* zt = (__hip_bfloat16*)bufA;

    const int TPB = 256;

    // ---- encoder spatial 1: x[6] -> h1[16]  (h1 = bufA)
    upsample_kernel<6, 16><<<(kN1 * 16 + TPB - 1) / TPB, TPB, 0, stream>>>(
        x, kN1, We1_u, be1_u, bufA);
    spatial_edge_kernel<6, 3, 16, 256><<<(kE1 * 16 + TPB - 1) / TPB, TPB, 0, stream>>>(
        x, ei1, kE1, ea1, We1_l, be1_l, bufA);

    // ---- encoder spatial 2: h1[16] -> h2[32]  (h2 = bufB)
    upsample_kernel<16, 32><<<(kN1 * 32 + TPB - 1) / TPB, TPB, 0, stream>>>(
        bufA, kN1, We2_u, be2_u, bufB);
    spatial_edge_kernel<16, 3, 32, 256><<<(kE1 * 32 + TPB - 1) / TPB, TPB, 0, stream>>>(
        bufA, ei1, kE1, ea1, We2_l, be2_l, bufB);

    // ---- encoder spatial 3: h2[32] -> h3[64]  (h3 = bufA)
    upsample_kernel<32, 64><<<(kN1 * 64 + TPB - 1) / TPB, TPB, 0, stream>>>(
        bufB, kN1, We3_u, be3_u, bufA);
    spatial_edge_kernel<32, 3, 64, 256><<<(kE1 * 64 + TPB - 1) / TPB, TPB, 0, stream>>>(
        bufB, ei1, kE1, ea1, We3_l, be3_l, bufA);

    // ---- encoder temporal (dim 64): s1 = bufB, cnt1 = bufC, z in-place bufB
    hipMemsetAsync(bufB, 0, (size_t)kN1 * 64 * sizeof(float), stream);
    hipMemsetAsync(bufC, 0, (size_t)kN1 * sizeof(float), stream);
    temporal_edge64_kernel<<<(kN1 + 3) / 4, 256, 0, stream>>>(
        bufA, tei1, kN1, Wt1, bt1, bufB, bufC);
    temporal_combine64_kernel<<<(kN1 * 64 + TPB - 1) / TPB, TPB, 0, stream>>>(
        bufB, bufC, bufA, bufB, kN1);

    // ---- transform GEMM: z(bufB as [65536,384]) @ W_tr^T -> tanh -> zt (bf16, bufA)
    {
        dim3 grid(kN / 64, kM / 64);
        gemm_tanh_kernel<<<grid, 256, 0, stream>>>(bufB, W_tr, b_tr, zt);
    }

    // ---- decoder spatial 1: x2[66] (virtual) -> d1[32]  (d1 = bufB)
    dec1_upsample_kernel<<<(kN2 * 32 + TPB - 1) / TPB, TPB, 0, stream>>>(
        zt, lower, upper, Wd1_u, bd1_u, bufB, kN2);
    dec1_edge_kernel<<<(kE2 * 32 + TPB - 1) / TPB, TPB, 0, stream>>>(
        zt, lower, upper, ei2, kE2, ea2, Wd1_l, bd1_l, bufB);

    // ---- decoder spatial 2: d1[32] -> d2[16]  (d2 = bufA as f32)
    float* d2 = (float*)bufA;
    upsample_kernel<32, 16><<<(kN2 * 16 + TPB - 1) / TPB, TPB, 0, stream>>>(
        bufB, kN2, Wd2_u, bd2_u, d2);
    spatial_edge_kernel<32, 6, 16, 256><<<(kE2 * 16 + TPB - 1) / TPB, TPB, 0, stream>>>(
        bufB, ei2, kE2, ea2, Wd2_l, bd2_l, d2);

    // ---- decoder spatial 3: d2[16] -> d3[1]  (d3 = bufB)
    float* d3 = bufB;
    upsample_kernel<16, 1><<<(kN2 + TPB - 1) / TPB, TPB, 0, stream>>>(
        d2, kN2, Wd3_u, bd3_u, d3);
    spatial_edge_kernel<16, 6, 1, 256><<<(kE2 + TPB - 1) / TPB, TPB, 0, stream>>>(
        d2, ei2, kE2, ea2, Wd3_l, bd3_l, d3);

    // ---- decoder temporal (dim 1) + final affine
    hipMemsetAsync(bufC, 0, (size_t)2 * kN2 * sizeof(float), stream);
    temporal_edge1_kernel<<<(kN2 + TPB - 1) / TPB, TPB, 0, stream>>>(
        d3, tei2, kN2, Wt2, bt2, bufC, bufC + kN2);
    final_kernel<<<(kN2 + TPB - 1) / TPB, TPB, 0, stream>>>(
        bufC, bufC + kN2, d3, lower, upper, (float*)d_out, kN2);
}

// Round 3
// 2501.725 us; speedup vs baseline: 1.9415x; 1.9415x over previous
//
#include <hip/hip_runtime.h>
#include <hip/hip_bf16.h>

// ---------------------------------------------------------------------------
// ArmNet forward. Round 3: kill LDS bank conflicts in temporal staging
// (native padded layout), LDS-stage all weight matrices (no per-lane global
// weight gathers), amortize staging with ITER loops, vectorize row gathers.
// ---------------------------------------------------------------------------

constexpr int kN1 = 393216;   // encoder nodes
constexpr int kE1 = 327680;   // encoder edges
constexpr int kN2 = 917504;   // decoder nodes
constexpr int kE2 = 851968;   // decoder edges
constexpr int kM  = 65536;    // B*PERIOD (transform GEMM rows)
constexpr int kK  = 384;      // transform K
constexpr int kN  = 896;      // transform N (14*64)

__device__ inline float2 bf2_unpack(unsigned u) {
    union { unsigned i; float f; } a, b;
    a.i = u << 16;           // element 2j   (low half)
    b.i = u & 0xffff0000u;   // element 2j+1 (high half)
    return make_float2(a.f, b.f);
}

// ---------------- generic spatial edge kernel ------------------------------
// out pre-filled with the residual (upsample) term; atomically add messages.
// z = [x_dst | x_src | ea], m = leaky_relu(Wl z + b, 0.01).
template<int IN, int EA, int OUT, int TPB, int ITER>
__global__ __launch_bounds__(TPB)
void spatial_edge_kernel(const float* __restrict__ x,
                         const int* __restrict__ ei, int E,
                         const float* __restrict__ ea,
                         const float* __restrict__ Wl,
                         const float* __restrict__ bl,
                         float* __restrict__ out)
{
    constexpr int Z  = 2 * IN + EA;
    constexpr int Zp = (Z % 2 == 0) ? Z + 1 : Z;   // odd stride: conflict-free
    constexpr int EPB = TPB / OUT;
    static_assert(TPB % OUT == 0, "TPB % OUT");
    __shared__ float sW[OUT * Zp];
    __shared__ float sB[OUT];
    for (int i = threadIdx.x; i < OUT * Z; i += TPB)
        sW[(i / Z) * Zp + (i % Z)] = Wl[i];
    for (int i = threadIdx.x; i < OUT; i += TPB) sB[i] = bl[i];
    __syncthreads();

    const int le = threadIdx.x / OUT;
    const int c  = threadIdx.x % OUT;
    const float* __restrict__ w = &sW[c * Zp];
    const int base = blockIdx.x * EPB * ITER;

    #pragma unroll 1
    for (int it = 0; it < ITER; ++it) {
        const int e = base + it * EPB + le;
        if (e >= E) break;
        const int src = ei[e];
        const int dst = ei[E + e];
        float acc = sB[c];
        if constexpr (IN % 4 == 0) {
            const float4* __restrict__ xd4 = (const float4*)&x[(long)dst * IN];
            const float4* __restrict__ xs4 = (const float4*)&x[(long)src * IN];
            #pragma unroll
            for (int q = 0; q < IN / 4; ++q) {
                const float4 v = xd4[q];
                acc = fmaf(w[4*q+0], v.x, acc); acc = fmaf(w[4*q+1], v.y, acc);
                acc = fmaf(w[4*q+2], v.z, acc); acc = fmaf(w[4*q+3], v.w, acc);
            }
            #pragma unroll
            for (int q = 0; q < IN / 4; ++q) {
                const float4 v = xs4[q];
                acc = fmaf(w[IN+4*q+0], v.x, acc); acc = fmaf(w[IN+4*q+1], v.y, acc);
                acc = fmaf(w[IN+4*q+2], v.z, acc); acc = fmaf(w[IN+4*q+3], v.w, acc);
            }
        } else {
            const float* __restrict__ xd = &x[(long)dst * IN];
            const float* __restrict__ xs = &x[(long)src * IN];
            #pragma unroll
            for (int j = 0; j < IN; ++j) acc = fmaf(w[j], xd[j], acc);
            #pragma unroll
            for (int j = 0; j < IN; ++j) acc = fmaf(w[IN + j], xs[j], acc);
        }
        const float* __restrict__ eav = &ea[(long)e * EA];
        #pragma unroll
        for (int j = 0; j < EA; ++j) acc = fmaf(w[2 * IN + j], eav[j], acc);
        acc = acc > 0.f ? acc : 0.01f * acc;     // leaky_relu(0.01)
        atomicAdd(&out[(long)dst * OUT + c], acc);
    }
}

// ---------------- generic upsample (residual linear) -----------------------
template<int IN, int OUT, int ITER>
__global__ __launch_bounds__(256)
void upsample_kernel(const float* __restrict__ x, int N,
                     const float* __restrict__ Wu,
                     const float* __restrict__ bu,
                     float* __restrict__ out)
{
    constexpr int INp = (IN % 2 == 0) ? IN + 1 : IN;
    __shared__ float sW[OUT * INp];
    __shared__ float sB[OUT];
    for (int i = threadIdx.x; i < OUT * IN; i += 256)
        sW[(i / IN) * INp + (i % IN)] = Wu[i];
    for (int i = threadIdx.x; i < OUT; i += 256) sB[i] = bu[i];
    __syncthreads();

    const int total = N * OUT;
    #pragma unroll 1
    for (int it = 0; it < ITER; ++it) {
        const int idx = (blockIdx.x * ITER + it) * 256 + threadIdx.x;
        if (idx >= total) break;
        const int n = idx / OUT, c = idx % OUT;
        const float* __restrict__ w = &sW[c * INp];
        float acc = sB[c];
        if constexpr (IN % 4 == 0) {
            const float4* __restrict__ xv4 = (const float4*)&x[(long)n * IN];
            #pragma unroll
            for (int q = 0; q < IN / 4; ++q) {
                const float4 v = xv4[q];
                acc = fmaf(w[4*q+0], v.x, acc); acc = fmaf(w[4*q+1], v.y, acc);
                acc = fmaf(w[4*q+2], v.z, acc); acc = fmaf(w[4*q+3], v.w, acc);
            }
        } else {
            const float* __restrict__ xv = &x[(long)n * IN];
            #pragma unroll
            for (int j = 0; j < IN; ++j) acc = fmaf(w[j], xv[j], acc);
        }
        out[idx] = acc;
    }
}

// ---------------- decoder layer-1 (virtual concat input) -------------------
// x2[n, j] = j<64 ? zt[n,j] (bf16) : j==64 ? lower[n] : upper[n]
template<int ITER>
__global__ __launch_bounds__(256)
void dec1_edge_kernel(const __hip_bfloat16* __restrict__ zt,
                      const float* __restrict__ lo, const float* __restrict__ up,
                      const int* __restrict__ ei, int E,
                      const float* __restrict__ ea,   // EA = 6
                      const float* __restrict__ Wl,   // [32, 138]
                      const float* __restrict__ bl,
                      float* __restrict__ out)        // [N2, 32]
{
    constexpr int OUT = 32, Z = 138, Zp = 139;
    __shared__ float sW[OUT * Zp];
    __shared__ float sB[OUT];
    for (int i = threadIdx.x; i < OUT * Z; i += 256)
        sW[(i / Z) * Zp + (i % Z)] = Wl[i];
    if (threadIdx.x < OUT) sB[threadIdx.x] = bl[threadIdx.x];
    __syncthreads();

    const int le = threadIdx.x >> 5;
    const int c  = threadIdx.x & 31;
    const float* __restrict__ w = &sW[c * Zp];
    const int base = blockIdx.x * 8 * ITER;

    #pragma unroll 1
    for (int it = 0; it < ITER; ++it) {
        const int e = base + it * 8 + le;
        if (e >= E) break;
        const int src = ei[e];
        const int dst = ei[E + e];
        float acc = sB[c];
        const unsigned* __restrict__ zd2 = (const unsigned*)&zt[(long)dst * 64];
        const unsigned* __restrict__ zs2 = (const unsigned*)&zt[(long)src * 64];
        #pragma unroll
        for (int q = 0; q < 32; ++q) {
            const float2 v = bf2_unpack(zd2[q]);
            acc = fmaf(w[2*q], v.x, acc); acc = fmaf(w[2*q+1], v.y, acc);
        }
        acc = fmaf(w[64], lo[dst], acc);
        acc = fmaf(w[65], up[dst], acc);
        #pragma unroll
        for (int q = 0; q < 32; ++q) {
            const float2 v = bf2_unpack(zs2[q]);
            acc = fmaf(w[66+2*q], v.x, acc); acc = fmaf(w[66+2*q+1], v.y, acc);
        }
        acc = fmaf(w[130], lo[src], acc);
        acc = fmaf(w[131], up[src], acc);
        const float* __restrict__ eav = &ea[(long)e * 6];
        #pragma unroll
        for (int j = 0; j < 6; ++j) acc = fmaf(w[132 + j], eav[j], acc);
        acc = acc > 0.f ? acc : 0.01f * acc;
        atomicAdd(&out[(long)dst * OUT + c], acc);
    }
}

template<int ITER>
__global__ __launch_bounds__(256)
void dec1_upsample_kernel(const __hip_bfloat16* __restrict__ zt,
                          const float* __restrict__ lo,
                          const float* __restrict__ up,
                          const float* __restrict__ Wu,  // [32, 66]
                          const float* __restrict__ bu,
                          float* __restrict__ out, int N)
{
    constexpr int IN = 66, INp = 67, OUT = 32;
    __shared__ float sW[OUT * INp];
    __shared__ float sB[OUT];
    for (int i = threadIdx.x; i < OUT * IN; i += 256)
        sW[(i / IN) * INp + (i % IN)] = Wu[i];
    if (threadIdx.x < OUT) sB[threadIdx.x] = bu[threadIdx.x];
    __syncthreads();

    const int total = N * OUT;
    #pragma unroll 1
    for (int it = 0; it < ITER; ++it) {
        const int idx = (blockIdx.x * ITER + it) * 256 + threadIdx.x;
        if (idx >= total) break;
        const int n = idx >> 5, c = idx & 31;
        const float* __restrict__ w = &sW[c * INp];
        const unsigned* __restrict__ zn2 = (const unsigned*)&zt[(long)n * 64];
        float acc = sB[c];
        #pragma unroll
        for (int q = 0; q < 32; ++q) {
            const float2 v = bf2_unpack(zn2[q]);
            acc = fmaf(w[2*q], v.x, acc); acc = fmaf(w[2*q+1], v.y, acc);
        }
        acc = fmaf(w[64], lo[n], acc);
        acc = fmaf(w[65], up[n], acc);
        out[idx] = acc;
    }
}

// ---------------- temporal blocks ------------------------------------------
// dim-64 (encoder): m = relu(Wt [x_dst|x_src] + bt), mean-aggregate by dst.
// Weights staged in NATIVE [64][128] layout padded to 129 (odd stride:
// conflict-free staging writes AND per-lane reads).
template<int ITER>
__global__ __launch_bounds__(256)
void temporal_edge64_kernel(const float* __restrict__ x,
                            const int* __restrict__ ei, int E,
                            const float* __restrict__ Wt,  // [64,128]
                            const float* __restrict__ bt,
                            float* __restrict__ s, float* __restrict__ cnt)
{
    constexpr int LD = 129;
    __shared__ float sW[64 * LD];   // 33 KB
    __shared__ float sB[64];
    for (int i = threadIdx.x; i < 64 * 128; i += 256)
        sW[(i >> 7) * LD + (i & 127)] = Wt[i];
    if (threadIdx.x < 64) sB[threadIdx.x] = bt[threadIdx.x];
    __syncthreads();

    const int le = threadIdx.x >> 6;
    const int c  = threadIdx.x & 63;
    const float* __restrict__ w = &sW[c * LD];
    const int base = blockIdx.x * 4 * ITER;

    #pragma unroll 1
    for (int it = 0; it < ITER; ++it) {
        const int e = base + it * 4 + le;
        if (e >= E) break;
        const int src = ei[e];
        const int dst = ei[E + e];
        const float4* __restrict__ xd4 = (const float4*)&x[(long)dst * 64];
        const float4* __restrict__ xs4 = (const float4*)&x[(long)src * 64];
        float acc = sB[c];
        #pragma unroll
        for (int q = 0; q < 16; ++q) {
            const float4 v = xd4[q];
            acc = fmaf(w[4*q+0], v.x, acc); acc = fmaf(w[4*q+1], v.y, acc);
            acc = fmaf(w[4*q+2], v.z, acc); acc = fmaf(w[4*q+3], v.w, acc);
        }
        #pragma unroll
        for (int q = 0; q < 16; ++q) {
            const float4 v = xs4[q];
            acc = fmaf(w[64+4*q+0], v.x, acc); acc = fmaf(w[64+4*q+1], v.y, acc);
            acc = fmaf(w[64+4*q+2], v.z, acc); acc = fmaf(w[64+4*q+3], v.w, acc);
        }
        acc = fmaxf(acc, 0.f);
        atomicAdd(&s[(long)dst * 64 + c], acc);
        if (c == 0) atomicAdd(&cnt[dst], 1.f);
    }
}

__global__ void temporal_combine64_kernel(const float* __restrict__ s,
                                          const float* __restrict__ cnt,
                                          const float* __restrict__ x,
                                          float* __restrict__ z, int N)
{
    int idx = blockIdx.x * blockDim.x + threadIdx.x;
    if (idx >= N * 64) return;
    const int n = idx >> 6;
    z[idx] = s[idx] / fmaxf(cnt[n], 1.f) + x[idx];
}

// dim-1 (decoder): trivial weights (Wt2 is [1,2]).
__global__ void temporal_edge1_kernel(const float* __restrict__ x,
                                      const int* __restrict__ ei, int E,
                                      const float* __restrict__ Wt,
                                      const float* __restrict__ bt,
                                      float* __restrict__ s, float* __restrict__ cnt)
{
    int e = blockIdx.x * blockDim.x + threadIdx.x;
    if (e >= E) return;
    const int src = ei[e];
    const int dst = ei[E + e];
    float m = Wt[0] * x[dst] + Wt[1] * x[src] + bt[0];
    m = fmaxf(m, 0.f);
    atomicAdd(&s[dst], m);
    atomicAdd(&cnt[dst], 1.f);
}

// ---------------- transform GEMM: [M,384] @ [384,896]^T + bias, tanh -> bf16
__global__ __launch_bounds__(256)
void gemm_tanh_kernel(const float* __restrict__ A,    // [M, 384]
                      const float* __restrict__ W,    // [896, 384]
                      const float* __restrict__ bias, // [896]
                      __hip_bfloat16* __restrict__ out) // [M, 896]
{
    constexpr int BM = 64, BN = 64, BK = 16, LDP = BM + 4;
    __shared__ float As[BK][LDP];
    __shared__ float Bs[BK][LDP];
    const int tid = threadIdx.x;
    const int tx = tid & 15, ty = tid >> 4;
    const int bm = blockIdx.y * BM;
    const int bn = blockIdx.x * BN;
    const int lr = tid >> 2;       // 0..63: tile row to stage
    const int lq = tid & 3;        // which float4 of the 16-wide K slice

    float acc[4][4] = {};
    for (int k0 = 0; k0 < kK; k0 += BK) {
        float4 a4 = *(const float4*)&A[(long)(bm + lr) * kK + k0 + lq * 4];
        float4 b4 = *(const float4*)&W[(long)(bn + lr) * kK + k0 + lq * 4];
        As[lq * 4 + 0][lr] = a4.x; As[lq * 4 + 1][lr] = a4.y;
        As[lq * 4 + 2][lr] = a4.z; As[lq * 4 + 3][lr] = a4.w;
        Bs[lq * 4 + 0][lr] = b4.x; Bs[lq * 4 + 1][lr] = b4.y;
        Bs[lq * 4 + 2][lr] = b4.z; Bs[lq * 4 + 3][lr] = b4.w;
        __syncthreads();
        #pragma unroll
        for (int k = 0; k < BK; ++k) {
            const float4 av = *(const float4*)&As[k][ty * 4];
            const float4 bv = *(const float4*)&Bs[k][tx * 4];
            const float a[4] = {av.x, av.y, av.z, av.w};
            const float b[4] = {bv.x, bv.y, bv.z, bv.w};
            #pragma unroll
            for (int i = 0; i < 4; ++i)
                #pragma unroll
                for (int j = 0; j < 4; ++j)
                    acc[i][j] = fmaf(a[i], b[j], acc[i][j]);
        }
        __syncthreads();
    }
    #pragma unroll
    for (int i = 0; i < 4; ++i) {
        const int row = bm + ty * 4 + i;
        #pragma unroll
        for (int j = 0; j < 4; ++j) {
            const int col = bn + tx * 4 + j;
            const float v = tanhf(acc[i][j] + bias[col]);
            out[(long)row * kN + col] = __float2bfloat16(v);
        }
    }
}

// ---------------- final: tanh(temporal) -> affine to joint range -----------
__global__ void final_kernel(const float* __restrict__ s,
                             const float* __restrict__ cnt,
                             const float* __restrict__ d3,
                             const float* __restrict__ lo,
                             const float* __restrict__ up,
                             float* __restrict__ out, int N)
{
    int i = blockIdx.x * blockDim.x + threadIdx.x;
    if (i >= N) return;
    const float t = s[i] / fmaxf(cnt[i], 1.f) + d3[i];
    const float o = tanhf(t);
    out[i] = lo[i] + (up[i] - lo[i]) * (o + 1.f) * 0.5f;
}

// ---------------------------------------------------------------------------
extern "C" void kernel_launch(void* const* d_in, const int* in_sizes, int n_in,
                              void* d_out, int out_size, void* d_ws, size_t ws_size,
                              hipStream_t stream)
{
    const float* x     = (const float*)d_in[0];
    const int*   ei1   = (const int*)  d_in[1];
    const float* ea1   = (const float*)d_in[2];
    const int*   tei1  = (const int*)  d_in[3];
    const float* lower = (const float*)d_in[4];
    const float* upper = (const float*)d_in[5];
    const int*   ei2   = (const int*)  d_in[6];
    const float* ea2   = (const float*)d_in[7];
    const int*   tei2  = (const int*)  d_in[8];
    const float* We1_l = (const float*)d_in[9];  const float* be1_l = (const float*)d_in[10];
    const float* We1_u = (const float*)d_in[11]; const float* be1_u = (const float*)d_in[12];
    const float* We2_l = (const float*)d_in[13]; const float* be2_l = (const float*)d_in[14];
    const float* We2_u = (const float*)d_in[15]; const float* be2_u = (const float*)d_in[16];
    const float* We3_l = (const float*)d_in[17]; const float* be3_l = (const float*)d_in[18];
    const float* We3_u = (const float*)d_in[19]; const float* be3_u = (const float*)d_in[20];
    const float* Wt1   = (const float*)d_in[21]; const float* bt1   = (const float*)d_in[22];
    const float* W_tr  = (const float*)d_in[23]; const float* b_tr  = (const float*)d_in[24];
    const float* Wd1_l = (const float*)d_in[25]; const float* bd1_l = (const float*)d_in[26];
    const float* Wd1_u = (const float*)d_in[27]; const float* bd1_u = (const float*)d_in[28];
    const float* Wd2_l = (const float*)d_in[29]; const float* bd2_l = (const float*)d_in[30];
    const float* Wd2_u = (const float*)d_in[31]; const float* bd2_u = (const float*)d_in[32];
    const float* Wd3_l = (const float*)d_in[33]; const float* bd3_l = (const float*)d_in[34];
    const float* Wd3_u = (const float*)d_in[35]; const float* bd3_u = (const float*)d_in[36];
    const float* Wt2   = (const float*)d_in[37]; const float* bt2   = (const float*)d_in[38];

    // workspace layout (bytes):
    //   bufA: 117,440,512   (holds h1/h3/zt(bf16)/d2)
    //   bufB: 117,440,512   (holds h2/s1/z/d1/d3)
    //   bufC:   7,340,032   (holds cnt1 | s2+cnt2)
    char* ws = (char*)d_ws;
    float* bufA = (float*)ws;
    float* bufB = (float*)(ws + 117440512);
    float* bufC = (float*)(ws + 234881024);
    __hip_bfloat16* zt = (__hip_bfloat16*)bufA;

    const int TPB = 256;
    auto cdiv = [](long a, long b) { return (int)((a + b - 1) / b); };

    // ---- encoder spatial 1: x[6] -> h1[16]  (h1 = bufA)
    upsample_kernel<6, 16, 8><<<cdiv((long)kN1 * 16, 2048), TPB, 0, stream>>>(
        x, kN1, We1_u, be1_u, bufA);
    spatial_edge_kernel<6, 3, 16, 256, 16><<<cdiv(kE1, 256), TPB, 0, stream>>>(
        x, ei1, kE1, ea1, We1_l, be1_l, bufA);

    // ---- encoder spatial 2: h1[16] -> h2[32]  (h2 = bufB)
    upsample_kernel<16, 32, 8><<<cdiv((long)kN1 * 32, 2048), TPB, 0, stream>>>(
        bufA, kN1, We2_u, be2_u, bufB);
    spatial_edge_kernel<16, 3, 32, 256, 16><<<cdiv(kE1, 128), TPB, 0, stream>>>(
        bufA, ei1, kE1, ea1, We2_l, be2_l, bufB);

    // ---- encoder spatial 3: h2[32] -> h3[64]  (h3 = bufA)
    upsample_kernel<32, 64, 8><<<cdiv((long)kN1 * 64, 2048), TPB, 0, stream>>>(
        bufB, kN1, We3_u, be3_u, bufA);
    spatial_edge_kernel<32, 3, 64, 256, 16><<<cdiv(kE1, 64), TPB, 0, stream>>>(
        bufB, ei1, kE1, ea1, We3_l, be3_l, bufA);

    // ---- encoder temporal (dim 64): s1 = bufB, cnt1 = bufC, z in-place bufB
    hipMemsetAsync(bufB, 0, (size_t)kN1 * 64 * sizeof(float), stream);
    hipMemsetAsync(bufC, 0, (size_t)kN1 * sizeof(float), stream);
    temporal_edge64_kernel<32><<<cdiv(kN1, 128), 256, 0, stream>>>(
        bufA, tei1, kN1, Wt1, bt1, bufB, bufC);
    temporal_combine64_kernel<<<cdiv((long)kN1 * 64, TPB), TPB, 0, stream>>>(
        bufB, bufC, bufA, bufB, kN1);

    // ---- transform GEMM: z(bufB as [65536,384]) @ W_tr^T -> tanh -> zt (bf16, bufA)
    {
        dim3 grid(kN / 64, kM / 64);
        gemm_tanh_kernel<<<grid, 256, 0, stream>>>(bufB, W_tr, b_tr, zt);
    }

    // ---- decoder spatial 1: x2[66] (virtual) -> d1[32]  (d1 = bufB)
    dec1_upsample_kernel<8><<<cdiv((long)kN2 * 32, 2048), TPB, 0, stream>>>(
        zt, lower, upper, Wd1_u, bd1_u, bufB, kN2);
    dec1_edge_kernel<16><<<cdiv(kE2, 128), TPB, 0, stream>>>(
        zt, lower, upper, ei2, kE2, ea2, Wd1_l, bd1_l, bufB);

    // ---- decoder spatial 2: d1[32] -> d2[16]  (d2 = bufA as f32)
    float* d2 = (float*)bufA;
    upsample_kernel<32, 16, 8><<<cdiv((long)kN2 * 16, 2048), TPB, 0, stream>>>(
        bufB, kN2, Wd2_u, bd2_u, d2);
    spatial_edge_kernel<32, 6, 16, 256, 16><<<cdiv(kE2, 256), TPB, 0, stream>>>(
        bufB, ei2, kE2, ea2, Wd2_l, bd2_l, d2);

    // ---- decoder spatial 3: d2[16] -> d3[1]  (d3 = bufB)
    float* d3 = bufB;
    upsample_kernel<16, 1, 8><<<cdiv(kN2, 2048), TPB, 0, stream>>>(
        d2, kN2, Wd3_u, bd3_u, d3);
    spatial_edge_kernel<16, 6, 1, 256, 4><<<cdiv(kE2, 1024), TPB, 0, stream>>>(
        d2, ei2, kE2, ea2, Wd3_l, bd3_l, d3);

    // ---- decoder temporal (dim 1) + final affine
    hipMemsetAsync(bufC, 0, (size_t)2 * kN2 * sizeof(float), stream);
    temporal_edge1_kernel<<<cdiv(kN2, TPB), TPB, 0, stream>>>(
        d3, tei2, kN2, Wt2, bt2, bufC, bufC + kN2);
    final_kernel<<<cdiv(kN2, TPB), TPB, 0, stream>>>(
        bufC, bufC + kN2, d3, lower, upper, (float*)d_out, kN2);
}

// Round 4
// 2026.139 us; speedup vs baseline: 2.3973x; 1.2347x over previous
//
#include <hip/hip_runtime.h>
#include <hip/hip_bf16.h>

// ---------------------------------------------------------------------------
// ArmNet forward. Round 4: transform GEMM -> bf16 MFMA (cast-on-stage),
// uint4-vectorized zt gathers in dec1 kernels, grid/ITER rebalance for
// latency-bound edge kernels.
// ---------------------------------------------------------------------------

constexpr int kN1 = 393216;   // encoder nodes
constexpr int kE1 = 327680;   // encoder edges
constexpr int kN2 = 917504;   // decoder nodes
constexpr int kE2 = 851968;   // decoder edges
constexpr int kM  = 65536;    // B*PERIOD (transform GEMM rows)
constexpr int kK  = 384;      // transform K
constexpr int kN  = 896;      // transform N (14*64)

typedef __attribute__((ext_vector_type(8))) short bf16x8;
typedef __attribute__((ext_vector_type(4))) float f32x4;

__device__ inline float2 bf2_unpack(unsigned u) {
    union { unsigned i; float f; } a, b;
    a.i = u << 16;           // element 2j   (low half)
    b.i = u & 0xffff0000u;   // element 2j+1 (high half)
    return make_float2(a.f, b.f);
}

__device__ inline ushort f2bf(float f) {   // RNE f32 -> bf16 (finite inputs)
    union { float f; unsigned u; } x; x.f = f;
    unsigned r = x.u + 0x7fffu + ((x.u >> 16) & 1u);
    return (ushort)(r >> 16);
}

__device__ inline void pack8(ushort* d, float4 u, float4 v) {
    bf16x8 p;
    p[0] = (short)f2bf(u.x); p[1] = (short)f2bf(u.y);
    p[2] = (short)f2bf(u.z); p[3] = (short)f2bf(u.w);
    p[4] = (short)f2bf(v.x); p[5] = (short)f2bf(v.y);
    p[6] = (short)f2bf(v.z); p[7] = (short)f2bf(v.w);
    *(bf16x8*)d = p;
}

// ---------------- generic spatial edge kernel ------------------------------
template<int IN, int EA, int OUT, int TPB, int ITER>
__global__ __launch_bounds__(TPB)
void spatial_edge_kernel(const float* __restrict__ x,
                         const int* __restrict__ ei, int E,
                         const float* __restrict__ ea,
                         const float* __restrict__ Wl,
                         const float* __restrict__ bl,
                         float* __restrict__ out)
{
    constexpr int Z  = 2 * IN + EA;
    constexpr int Zp = (Z % 2 == 0) ? Z + 1 : Z;   // odd stride: conflict-free
    constexpr int EPB = TPB / OUT;
    static_assert(TPB % OUT == 0, "TPB % OUT");
    __shared__ float sW[OUT * Zp];
    __shared__ float sB[OUT];
    for (int i = threadIdx.x; i < OUT * Z; i += TPB)
        sW[(i / Z) * Zp + (i % Z)] = Wl[i];
    for (int i = threadIdx.x; i < OUT; i += TPB) sB[i] = bl[i];
    __syncthreads();

    const int le = threadIdx.x / OUT;
    const int c  = threadIdx.x % OUT;
    const float* __restrict__ w = &sW[c * Zp];
    const int base = blockIdx.x * EPB * ITER;

    #pragma unroll 1
    for (int it = 0; it < ITER; ++it) {
        const int e = base + it * EPB + le;
        if (e >= E) break;
        const int src = ei[e];
        const int dst = ei[E + e];
        float acc = sB[c];
        if constexpr (IN % 4 == 0) {
            const float4* __restrict__ xd4 = (const float4*)&x[(long)dst * IN];
            const float4* __restrict__ xs4 = (const float4*)&x[(long)src * IN];
            #pragma unroll
            for (int q = 0; q < IN / 4; ++q) {
                const float4 v = xd4[q];
                acc = fmaf(w[4*q+0], v.x, acc); acc = fmaf(w[4*q+1], v.y, acc);
                acc = fmaf(w[4*q+2], v.z, acc); acc = fmaf(w[4*q+3], v.w, acc);
            }
            #pragma unroll
            for (int q = 0; q < IN / 4; ++q) {
                const float4 v = xs4[q];
                acc = fmaf(w[IN+4*q+0], v.x, acc); acc = fmaf(w[IN+4*q+1], v.y, acc);
                acc = fmaf(w[IN+4*q+2], v.z, acc); acc = fmaf(w[IN+4*q+3], v.w, acc);
            }
        } else {
            const float* __restrict__ xd = &x[(long)dst * IN];
            const float* __restrict__ xs = &x[(long)src * IN];
            #pragma unroll
            for (int j = 0; j < IN; ++j) acc = fmaf(w[j], xd[j], acc);
            #pragma unroll
            for (int j = 0; j < IN; ++j) acc = fmaf(w[IN + j], xs[j], acc);
        }
        const float* __restrict__ eav = &ea[(long)e * EA];
        #pragma unroll
        for (int j = 0; j < EA; ++j) acc = fmaf(w[2 * IN + j], eav[j], acc);
        acc = acc > 0.f ? acc : 0.01f * acc;     // leaky_relu(0.01)
        atomicAdd(&out[(long)dst * OUT + c], acc);
    }
}

// ---------------- generic upsample (residual linear) -----------------------
template<int IN, int OUT, int ITER>
__global__ __launch_bounds__(256)
void upsample_kernel(const float* __restrict__ x, int N,
                     const float* __restrict__ Wu,
                     const float* __restrict__ bu,
                     float* __restrict__ out)
{
    constexpr int INp = (IN % 2 == 0) ? IN + 1 : IN;
    __shared__ float sW[OUT * INp];
    __shared__ float sB[OUT];
    for (int i = threadIdx.x; i < OUT * IN; i += 256)
        sW[(i / IN) * INp + (i % IN)] = Wu[i];
    for (int i = threadIdx.x; i < OUT; i += 256) sB[i] = bu[i];
    __syncthreads();

    const int total = N * OUT;
    #pragma unroll 1
    for (int it = 0; it < ITER; ++it) {
        const int idx = (blockIdx.x * ITER + it) * 256 + threadIdx.x;
        if (idx >= total) break;
        const int n = idx / OUT, c = idx % OUT;
        const float* __restrict__ w = &sW[c * INp];
        float acc = sB[c];
        if constexpr (IN % 4 == 0) {
            const float4* __restrict__ xv4 = (const float4*)&x[(long)n * IN];
            #pragma unroll
            for (int q = 0; q < IN / 4; ++q) {
                const float4 v = xv4[q];
                acc = fmaf(w[4*q+0], v.x, acc); acc = fmaf(w[4*q+1], v.y, acc);
                acc = fmaf(w[4*q+2], v.z, acc); acc = fmaf(w[4*q+3], v.w, acc);
            }
        } else {
            const float* __restrict__ xv = &x[(long)n * IN];
            #pragma unroll
            for (int j = 0; j < IN; ++j) acc = fmaf(w[j], xv[j], acc);
        }
        out[idx] = acc;
    }
}

// ---------------- decoder layer-1 (virtual concat input) -------------------
// x2[n, j] = j<64 ? zt[n,j] (bf16) : j==64 ? lower[n] : upper[n]
template<int ITER>
__global__ __launch_bounds__(256)
void dec1_edge_kernel(const __hip_bfloat16* __restrict__ zt,
                      const float* __restrict__ lo, const float* __restrict__ up,
                      const int* __restrict__ ei, int E,
                      const float* __restrict__ ea,   // EA = 6
                      const float* __restrict__ Wl,   // [32, 138]
                      const float* __restrict__ bl,
                      float* __restrict__ out)        // [N2, 32]
{
    constexpr int OUT = 32, Z = 138, Zp = 139;
    __shared__ float sW[OUT * Zp];
    __shared__ float sB[OUT];
    for (int i = threadIdx.x; i < OUT * Z; i += 256)
        sW[(i / Z) * Zp + (i % Z)] = Wl[i];
    if (threadIdx.x < OUT) sB[threadIdx.x] = bl[threadIdx.x];
    __syncthreads();

    const int le = threadIdx.x >> 5;
    const int c  = threadIdx.x & 31;
    const float* __restrict__ w = &sW[c * Zp];
    const int base = blockIdx.x * 8 * ITER;

    #pragma unroll 1
    for (int it = 0; it < ITER; ++it) {
        const int e = base + it * 8 + le;
        if (e >= E) break;
        const int src = ei[e];
        const int dst = ei[E + e];
        float acc = sB[c];
        const uint4* __restrict__ zd4 = (const uint4*)&zt[(long)dst * 64];
        const uint4* __restrict__ zs4 = (const uint4*)&zt[(long)src * 64];
        #pragma unroll
        for (int q = 0; q < 8; ++q) {
            const uint4 u = zd4[q];
            float2 v;
            v = bf2_unpack(u.x); acc = fmaf(w[8*q+0], v.x, acc); acc = fmaf(w[8*q+1], v.y, acc);
            v = bf2_unpack(u.y); acc = fmaf(w[8*q+2], v.x, acc); acc = fmaf(w[8*q+3], v.y, acc);
            v = bf2_unpack(u.z); acc = fmaf(w[8*q+4], v.x, acc); acc = fmaf(w[8*q+5], v.y, acc);
            v = bf2_unpack(u.w); acc = fmaf(w[8*q+6], v.x, acc); acc = fmaf(w[8*q+7], v.y, acc);
        }
        acc = fmaf(w[64], lo[dst], acc);
        acc = fmaf(w[65], up[dst], acc);
        #pragma unroll
        for (int q = 0; q < 8; ++q) {
            const uint4 u = zs4[q];
            float2 v;
            v = bf2_unpack(u.x); acc = fmaf(w[66+8*q+0], v.x, acc); acc = fmaf(w[66+8*q+1], v.y, acc);
            v = bf2_unpack(u.y); acc = fmaf(w[66+8*q+2], v.x, acc); acc = fmaf(w[66+8*q+3], v.y, acc);
            v = bf2_unpack(u.z); acc = fmaf(w[66+8*q+4], v.x, acc); acc = fmaf(w[66+8*q+5], v.y, acc);
            v = bf2_unpack(u.w); acc = fmaf(w[66+8*q+6], v.x, acc); acc = fmaf(w[66+8*q+7], v.y, acc);
        }
        acc = fmaf(w[130], lo[src], acc);
        acc = fmaf(w[131], up[src], acc);
        const float* __restrict__ eav = &ea[(long)e * 6];
        #pragma unroll
        for (int j = 0; j < 6; ++j) acc = fmaf(w[132 + j], eav[j], acc);
        acc = acc > 0.f ? acc : 0.01f * acc;
        atomicAdd(&out[(long)dst * OUT + c], acc);
    }
}

template<int ITER>
__global__ __launch_bounds__(256)
void dec1_upsample_kernel(const __hip_bfloat16* __restrict__ zt,
                          const float* __restrict__ lo,
                          const float* __restrict__ up,
                          const float* __restrict__ Wu,  // [32, 66]
                          const float* __restrict__ bu,
                          float* __restrict__ out, int N)
{
    constexpr int IN = 66, INp = 67, OUT = 32;
    __shared__ float sW[OUT * INp];
    __shared__ float sB[OUT];
    for (int i = threadIdx.x; i < OUT * IN; i += 256)
        sW[(i / IN) * INp + (i % IN)] = Wu[i];
    if (threadIdx.x < OUT) sB[threadIdx.x] = bu[threadIdx.x];
    __syncthreads();

    const int total = N * OUT;
    #pragma unroll 1
    for (int it = 0; it < ITER; ++it) {
        const int idx = (blockIdx.x * ITER + it) * 256 + threadIdx.x;
        if (idx >= total) break;
        const int n = idx >> 5, c = idx & 31;
        const float* __restrict__ w = &sW[c * INp];
        const uint4* __restrict__ zn4 = (const uint4*)&zt[(long)n * 64];
        float acc = sB[c];
        #pragma unroll
        for (int q = 0; q < 8; ++q) {
            const uint4 u = zn4[q];
            float2 v;
            v = bf2_unpack(u.x); acc = fmaf(w[8*q+0], v.x, acc); acc = fmaf(w[8*q+1], v.y, acc);
            v = bf2_unpack(u.y); acc = fmaf(w[8*q+2], v.x, acc); acc = fmaf(w[8*q+3], v.y, acc);
            v = bf2_unpack(u.z); acc = fmaf(w[8*q+4], v.x, acc); acc = fmaf(w[8*q+5], v.y, acc);
            v = bf2_unpack(u.w); acc = fmaf(w[8*q+6], v.x, acc); acc = fmaf(w[8*q+7], v.y, acc);
        }
        acc = fmaf(w[64], lo[n], acc);
        acc = fmaf(w[65], up[n], acc);
        out[idx] = acc;
    }
}

// ---------------- temporal blocks ------------------------------------------
template<int ITER>
__global__ __launch_bounds__(256)
void temporal_edge64_kernel(const float* __restrict__ x,
                            const int* __restrict__ ei, int E,
                            const float* __restrict__ Wt,  // [64,128]
                            const float* __restrict__ bt,
                            float* __restrict__ s, float* __restrict__ cnt)
{
    constexpr int LD = 129;
    __shared__ float sW[64 * LD];   // 33 KB
    __shared__ float sB[64];
    for (int i = threadIdx.x; i < 64 * 128; i += 256)
        sW[(i >> 7) * LD + (i & 127)] = Wt[i];
    if (threadIdx.x < 64) sB[threadIdx.x] = bt[threadIdx.x];
    __syncthreads();

    const int le = threadIdx.x >> 6;
    const int c  = threadIdx.x & 63;
    const float* __restrict__ w = &sW[c * LD];
    const int base = blockIdx.x * 4 * ITER;

    #pragma unroll 1
    for (int it = 0; it < ITER; ++it) {
        const int e = base + it * 4 + le;
        if (e >= E) break;
        const int src = ei[e];
        const int dst = ei[E + e];
        const float4* __restrict__ xd4 = (const float4*)&x[(long)dst * 64];
        const float4* __restrict__ xs4 = (const float4*)&x[(long)src * 64];
        float acc = sB[c];
        #pragma unroll
        for (int q = 0; q < 16; ++q) {
            const float4 v = xd4[q];
            acc = fmaf(w[4*q+0], v.x, acc); acc = fmaf(w[4*q+1], v.y, acc);
            acc = fmaf(w[4*q+2], v.z, acc); acc = fmaf(w[4*q+3], v.w, acc);
        }
        #pragma unroll
        for (int q = 0; q < 16; ++q) {
            const float4 v = xs4[q];
            acc = fmaf(w[64+4*q+0], v.x, acc); acc = fmaf(w[64+4*q+1], v.y, acc);
            acc = fmaf(w[64+4*q+2], v.z, acc); acc = fmaf(w[64+4*q+3], v.w, acc);
        }
        acc = fmaxf(acc, 0.f);
        atomicAdd(&s[(long)dst * 64 + c], acc);
        if (c == 0) atomicAdd(&cnt[dst], 1.f);
    }
}

__global__ void temporal_combine64_kernel(const float* __restrict__ s,
                                          const float* __restrict__ cnt,
                                          const float* __restrict__ x,
                                          float* __restrict__ z, int N)
{
    int idx = blockIdx.x * blockDim.x + threadIdx.x;
    if (idx >= N * 64) return;
    const int n = idx >> 6;
    z[idx] = s[idx] / fmaxf(cnt[n], 1.f) + x[idx];
}

__global__ void temporal_edge1_kernel(const float* __restrict__ x,
                                      const int* __restrict__ ei, int E,
                                      const float* __restrict__ Wt,
                                      const float* __restrict__ bt,
                                      float* __restrict__ s, float* __restrict__ cnt)
{
    int e = blockIdx.x * blockDim.x + threadIdx.x;
    if (e >= E) return;
    const int src = ei[e];
    const int dst = ei[E + e];
    float m = Wt[0] * x[dst] + Wt[1] * x[src] + bt[0];
    m = fmaxf(m, 0.f);
    atomicAdd(&s[dst], m);
    atomicAdd(&cnt[dst], 1.f);
}

// ---------------- transform GEMM (bf16 MFMA, cast on stage) ----------------
// A[M,384] f32, W[896,384] f32 -> out[M,896] bf16 = tanh(A W^T + bias)
// 128x128x32 tile, 4 waves (2x2), each wave 64x64 via 4x4 16x16x32 frags.
__global__ __launch_bounds__(256)
void gemm_mfma_tanh_kernel(const float* __restrict__ A,
                           const float* __restrict__ W,
                           const float* __restrict__ bias,
                           __hip_bfloat16* __restrict__ out)
{
    constexpr int BM = 128, LDP = 40;   // ushort pitch: 80B rows, 2-way banks
    __shared__ ushort sA[BM * LDP];
    __shared__ ushort sB[BM * LDP];
    const int tid  = threadIdx.x;
    const int lane = tid & 63;
    const int wid  = tid >> 6;
    const int wr = wid >> 1, wc = wid & 1;
    const long bm = (long)blockIdx.y * BM;
    const long bn = (long)blockIdx.x * BM;

    const int sr = tid >> 1;      // 0..127: staged tile row
    const int sh = tid & 1;       // 0/1: which 16-element k-half
    const float* __restrict__ gA = &A[(bm + sr) * kK + sh * 16];
    const float* __restrict__ gB = &W[(bn + sr) * kK + sh * 16];
    ushort* dA = &sA[sr * LDP + sh * 16];
    ushort* dB = &sB[sr * LDP + sh * 16];

    f32x4 acc[4][4] = {};
    const int g    = lane >> 4;   // k-group (8 bf16 each)
    const int rsel = lane & 15;

    for (int k0 = 0; k0 < kK; k0 += 32) {
        const float4 a0 = *(const float4*)(gA + k0 + 0);
        const float4 a1 = *(const float4*)(gA + k0 + 4);
        const float4 a2 = *(const float4*)(gA + k0 + 8);
        const float4 a3 = *(const float4*)(gA + k0 + 12);
        const float4 b0 = *(const float4*)(gB + k0 + 0);
        const float4 b1 = *(const float4*)(gB + k0 + 4);
        const float4 b2 = *(const float4*)(gB + k0 + 8);
        const float4 b3 = *(const float4*)(gB + k0 + 12);
        __syncthreads();                      // previous tile fully consumed
        pack8(dA, a0, a1); pack8(dA + 8, a2, a3);
        pack8(dB, b0, b1); pack8(dB + 8, b2, b3);
        __syncthreads();

        bf16x8 af[4], bfm[4];
        #pragma unroll
        for (int m = 0; m < 4; ++m)
            af[m] = *(const bf16x8*)&sA[(wr * 64 + m * 16 + rsel) * LDP + g * 8];
        #pragma unroll
        for (int n = 0; n < 4; ++n)
            bfm[n] = *(const bf16x8*)&sB[(wc * 64 + n * 16 + rsel) * LDP + g * 8];
        #pragma unroll
        for (int m = 0; m < 4; ++m)
            #pragma unroll
            for (int n = 0; n < 4; ++n)
                acc[m][n] = __builtin_amdgcn_mfma_f32_16x16x32_bf16(
                    af[m], bfm[n], acc[m][n], 0, 0, 0);
    }

    // epilogue: D frag col = lane&15, row = (lane>>4)*4 + reg
    const long colb = bn + wc * 64 + (lane & 15);
    const long rowb = bm + wr * 64 + (lane >> 4) * 4;
    #pragma unroll
    for (int n = 0; n < 4; ++n) {
        const long col = colb + n * 16;
        const float bs = bias[col];
        #pragma unroll
        for (int m = 0; m < 4; ++m) {
            #pragma unroll
            for (int r = 0; r < 4; ++r) {
                const float v = tanhf(acc[m][n][r] + bs);
                out[(rowb + m * 16 + r) * kN + col] = __float2bfloat16(v);
            }
        }
    }
}

// ---------------- final: tanh(temporal) -> affine to joint range -----------
__global__ void final_kernel(const float* __restrict__ s,
                             const float* __restrict__ cnt,
                             const float* __restrict__ d3,
                             const float* __restrict__ lo,
                             const float* __restrict__ up,
                             float* __restrict__ out, int N)
{
    int i = blockIdx.x * blockDim.x + threadIdx.x;
    if (i >= N) return;
    const float t = s[i] / fmaxf(cnt[i], 1.f) + d3[i];
    const float o = tanhf(t);
    out[i] = lo[i] + (up[i] - lo[i]) * (o + 1.f) * 0.5f;
}

// ---------------------------------------------------------------------------
extern "C" void kernel_launch(void* const* d_in, const int* in_sizes, int n_in,
                              void* d_out, int out_size, void* d_ws, size_t ws_size,
                              hipStream_t stream)
{
    const float* x     = (const float*)d_in[0];
    const int*   ei1   = (const int*)  d_in[1];
    const float* ea1   = (const float*)d_in[2];
    const int*   tei1  = (const int*)  d_in[3];
    const float* lower = (const float*)d_in[4];
    const float* upper = (const float*)d_in[5];
    const int*   ei2   = (const int*)  d_in[6];
    const float* ea2   = (const float*)d_in[7];
    const int*   tei2  = (const int*)  d_in[8];
    const float* We1_l = (const float*)d_in[9];  const float* be1_l = (const float*)d_in[10];
    const float* We1_u = (const float*)d_in[11]; const float* be1_u = (const float*)d_in[12];
    const float* We2_l = (const float*)d_in[13]; const float* be2_l = (const float*)d_in[14];
    const float* We2_u = (const float*)d_in[15]; const float* be2_u = (const float*)d_in[16];
    const float* We3_l = (const float*)d_in[17]; const float* be3_l = (const float*)d_in[18];
    const float* We3_u = (const float*)d_in[19]; const float* be3_u = (const float*)d_in[20];
    const float* Wt1   = (const float*)d_in[21]; const float* bt1   = (const float*)d_in[22];
    const float* W_tr  = (const float*)d_in[23]; const float* b_tr  = (const float*)d_in[24];
    const float* Wd1_l = (const float*)d_in[25]; const float* bd1_l = (const float*)d_in[26];
    const float* Wd1_u = (const float*)d_in[27]; const float* bd1_u = (const float*)d_in[28];
    const float* Wd2_l = (const float*)d_in[29]; const float* bd2_l = (const float*)d_in[30];
    const float* Wd2_u = (const float*)d_in[31]; const float* bd2_u = (const float*)d_in[32];
    const float* Wd3_l = (const float*)d_in[33]; const float* bd3_l = (const float*)d_in[34];
    const float* Wd3_u = (const float*)d_in[35]; const float* bd3_u = (const float*)d_in[36];
    const float* Wt2   = (const float*)d_in[37]; const float* bt2   = (const float*)d_in[38];

    // workspace layout (bytes):
    //   bufA: 117,440,512   (holds h1/h3/zt(bf16)/d2)
    //   bufB: 117,440,512   (holds h2/s1/z/d1/d3)
    //   bufC:   7,340,032   (holds cnt1 | s2+cnt2)
    char* ws = (char*)d_ws;
    float* bufA = (float*)ws;
    float* bufB = (float*)(ws + 117440512);
    float* bufC = (float*)(ws + 234881024);
    __hip_bfloat16* zt = (__hip_bfloat16*)bufA;

    const int TPB = 256;
    auto cdiv = [](long a, long b) { return (int)((a + b - 1) / b); };

    // ---- encoder spatial 1: x[6] -> h1[16]  (h1 = bufA)
    upsample_kernel<6, 16, 8><<<cdiv((long)kN1 * 16, 2048), TPB, 0, stream>>>(
        x, kN1, We1_u, be1_u, bufA);
    spatial_edge_kernel<6, 3, 16, 256, 4><<<cdiv(kE1, 64), TPB, 0, stream>>>(
        x, ei1, kE1, ea1, We1_l, be1_l, bufA);

    // ---- encoder spatial 2: h1[16] -> h2[32]  (h2 = bufB)
    upsample_kernel<16, 32, 8><<<cdiv((long)kN1 * 32, 2048), TPB, 0, stream>>>(
        bufA, kN1, We2_u, be2_u, bufB);
    spatial_edge_kernel<16, 3, 32, 256, 4><<<cdiv(kE1, 32), TPB, 0, stream>>>(
        bufA, ei1, kE1, ea1, We2_l, be2_l, bufB);

    // ---- encoder spatial 3: h2[32] -> h3[64]  (h3 = bufA)
    upsample_kernel<32, 64, 8><<<cdiv((long)kN1 * 64, 2048), TPB, 0, stream>>>(
        bufB, kN1, We3_u, be3_u, bufA);
    spatial_edge_kernel<32, 3, 64, 256, 8><<<cdiv(kE1, 32), TPB, 0, stream>>>(
        bufB, ei1, kE1, ea1, We3_l, be3_l, bufA);

    // ---- encoder temporal (dim 64): s1 = bufB, cnt1 = bufC, z in-place bufB
    hipMemsetAsync(bufB, 0, (size_t)kN1 * 64 * sizeof(float), stream);
    hipMemsetAsync(bufC, 0, (size_t)kN1 * sizeof(float), stream);
    temporal_edge64_kernel<32><<<cdiv(kN1, 128), 256, 0, stream>>>(
        bufA, tei1, kN1, Wt1, bt1, bufB, bufC);
    temporal_combine64_kernel<<<cdiv((long)kN1 * 64, TPB), TPB, 0, stream>>>(
        bufB, bufC, bufA, bufB, kN1);

    // ---- transform GEMM: z(bufB [65536,384] f32) @ W_tr^T -> tanh -> zt bf16
    {
        dim3 grid(kN / 128, kM / 128);
        gemm_mfma_tanh_kernel<<<grid, 256, 0, stream>>>(bufB, W_tr, b_tr, zt);
    }

    // ---- decoder spatial 1: x2[66] (virtual) -> d1[32]  (d1 = bufB)
    dec1_upsample_kernel<8><<<cdiv((long)kN2 * 32, 2048), TPB, 0, stream>>>(
        zt, lower, upper, Wd1_u, bd1_u, bufB, kN2);
    dec1_edge_kernel<8><<<cdiv(kE2, 64), TPB, 0, stream>>>(
        zt, lower, upper, ei2, kE2, ea2, Wd1_l, bd1_l, bufB);

    // ---- decoder spatial 2: d1[32] -> d2[16]  (d2 = bufA as f32)
    float* d2 = (float*)bufA;
    upsample_kernel<32, 16, 8><<<cdiv((long)kN2 * 16, 2048), TPB, 0, stream>>>(
        bufB, kN2, Wd2_u, bd2_u, d2);
    spatial_edge_kernel<32, 6, 16, 256, 4><<<cdiv(kE2, 64), TPB, 0, stream>>>(
        bufB, ei2, kE2, ea2, Wd2_l, bd2_l, d2);

    // ---- decoder spatial 3: d2[16] -> d3[1]  (d3 = bufB)
    float* d3 = bufB;
    upsample_kernel<16, 1, 8><<<cdiv(kN2, 2048), TPB, 0, stream>>>(
        d2, kN2, Wd3_u, bd3_u, d3);
    spatial_edge_kernel<16, 6, 1, 256, 1><<<cdiv(kE2, 256), TPB, 0, stream>>>(
        d2, ei2, kE2, ea2, Wd3_l, bd3_l, d3);

    // ---- decoder temporal (dim 1) + final affine
    hipMemsetAsync(bufC, 0, (size_t)2 * kN2 * sizeof(float), stream);
    temporal_edge1_kernel<<<cdiv(kN2, TPB), TPB, 0, stream>>>(
        d3, tei2, kN2, Wt2, bt2, bufC, bufC + kN2);
    final_kernel<<<cdiv(kN2, TPB), TPB, 0, stream>>>(
        bufC, bufC + kN2, d3, lower, upper, (float*)d_out, kN2);
}

// Round 5
// 2006.181 us; speedup vs baseline: 2.4211x; 1.0099x over previous
//
#include <hip/hip_runtime.h>
#include <hip/hip_bf16.h>

// ---------------------------------------------------------------------------
// ArmNet forward. Round 5: temporal64 + dec1_edge weight matrices stored in
// LDS as packed bf16 pairs in transposed [j-pair][channel] layout -> halves
// LDS bytes and LDS instruction count (the measured bottleneck), multi-
// accumulator ILP. Rest unchanged from round 4.
// ---------------------------------------------------------------------------

constexpr int kN1 = 393216;   // encoder nodes
constexpr int kE1 = 327680;   // encoder edges
constexpr int kN2 = 917504;   // decoder nodes
constexpr int kE2 = 851968;   // decoder edges
constexpr int kM  = 65536;    // B*PERIOD (transform GEMM rows)
constexpr int kK  = 384;      // transform K
constexpr int kN  = 896;      // transform N (14*64)

typedef __attribute__((ext_vector_type(8))) short bf16x8;
typedef __attribute__((ext_vector_type(4))) float f32x4;

__device__ inline float2 bf2_unpack(unsigned u) {
    union { unsigned i; float f; } a, b;
    a.i = u << 16;           // element 2j   (low half)
    b.i = u & 0xffff0000u;   // element 2j+1 (high half)
    return make_float2(a.f, b.f);
}

__device__ inline ushort f2bf(float f) {   // RNE f32 -> bf16 (finite inputs)
    union { float f; unsigned u; } x; x.f = f;
    unsigned r = x.u + 0x7fffu + ((x.u >> 16) & 1u);
    return (ushort)(r >> 16);
}

__device__ inline unsigned packbf2(float lo, float hi) {
    return (unsigned)f2bf(lo) | ((unsigned)f2bf(hi) << 16);
}

__device__ inline void pack8(ushort* d, float4 u, float4 v) {
    bf16x8 p;
    p[0] = (short)f2bf(u.x); p[1] = (short)f2bf(u.y);
    p[2] = (short)f2bf(u.z); p[3] = (short)f2bf(u.w);
    p[4] = (short)f2bf(v.x); p[5] = (short)f2bf(v.y);
    p[6] = (short)f2bf(v.z); p[7] = (short)f2bf(v.w);
    *(bf16x8*)d = p;
}

// ---------------- generic spatial edge kernel ------------------------------
template<int IN, int EA, int OUT, int TPB, int ITER>
__global__ __launch_bounds__(TPB)
void spatial_edge_kernel(const float* __restrict__ x,
                         const int* __restrict__ ei, int E,
                         const float* __restrict__ ea,
                         const float* __restrict__ Wl,
                         const float* __restrict__ bl,
                         float* __restrict__ out)
{
    constexpr int Z  = 2 * IN + EA;
    constexpr int Zp = (Z % 2 == 0) ? Z + 1 : Z;   // odd stride: conflict-free
    constexpr int EPB = TPB / OUT;
    static_assert(TPB % OUT == 0, "TPB % OUT");
    __shared__ float sW[OUT * Zp];
    __shared__ float sB[OUT];
    for (int i = threadIdx.x; i < OUT * Z; i += TPB)
        sW[(i / Z) * Zp + (i % Z)] = Wl[i];
    for (int i = threadIdx.x; i < OUT; i += TPB) sB[i] = bl[i];
    __syncthreads();

    const int le = threadIdx.x / OUT;
    const int c  = threadIdx.x % OUT;
    const float* __restrict__ w = &sW[c * Zp];
    const int base = blockIdx.x * EPB * ITER;

    #pragma unroll 1
    for (int it = 0; it < ITER; ++it) {
        const int e = base + it * EPB + le;
        if (e >= E) break;
        const int src = ei[e];
        const int dst = ei[E + e];
        float acc = sB[c];
        if constexpr (IN % 4 == 0) {
            const float4* __restrict__ xd4 = (const float4*)&x[(long)dst * IN];
            const float4* __restrict__ xs4 = (const float4*)&x[(long)src * IN];
            #pragma unroll
            for (int q = 0; q < IN / 4; ++q) {
                const float4 v = xd4[q];
                acc = fmaf(w[4*q+0], v.x, acc); acc = fmaf(w[4*q+1], v.y, acc);
                acc = fmaf(w[4*q+2], v.z, acc); acc = fmaf(w[4*q+3], v.w, acc);
            }
            #pragma unroll
            for (int q = 0; q < IN / 4; ++q) {
                const float4 v = xs4[q];
                acc = fmaf(w[IN+4*q+0], v.x, acc); acc = fmaf(w[IN+4*q+1], v.y, acc);
                acc = fmaf(w[IN+4*q+2], v.z, acc); acc = fmaf(w[IN+4*q+3], v.w, acc);
            }
        } else {
            const float* __restrict__ xd = &x[(long)dst * IN];
            const float* __restrict__ xs = &x[(long)src * IN];
            #pragma unroll
            for (int j = 0; j < IN; ++j) acc = fmaf(w[j], xd[j], acc);
            #pragma unroll
            for (int j = 0; j < IN; ++j) acc = fmaf(w[IN + j], xs[j], acc);
        }
        const float* __restrict__ eav = &ea[(long)e * EA];
        #pragma unroll
        for (int j = 0; j < EA; ++j) acc = fmaf(w[2 * IN + j], eav[j], acc);
        acc = acc > 0.f ? acc : 0.01f * acc;     // leaky_relu(0.01)
        atomicAdd(&out[(long)dst * OUT + c], acc);
    }
}

// ---------------- generic upsample (residual linear) -----------------------
template<int IN, int OUT, int ITER>
__global__ __launch_bounds__(256)
void upsample_kernel(const float* __restrict__ x, int N,
                     const float* __restrict__ Wu,
                     const float* __restrict__ bu,
                     float* __restrict__ out)
{
    constexpr int INp = (IN % 2 == 0) ? IN + 1 : IN;
    __shared__ float sW[OUT * INp];
    __shared__ float sB[OUT];
    for (int i = threadIdx.x; i < OUT * IN; i += 256)
        sW[(i / IN) * INp + (i % IN)] = Wu[i];
    for (int i = threadIdx.x; i < OUT; i += 256) sB[i] = bu[i];
    __syncthreads();

    const int total = N * OUT;
    #pragma unroll 1
    for (int it = 0; it < ITER; ++it) {
        const int idx = (blockIdx.x * ITER + it) * 256 + threadIdx.x;
        if (idx >= total) break;
        const int n = idx / OUT, c = idx % OUT;
        const float* __restrict__ w = &sW[c * INp];
        float acc = sB[c];
        if constexpr (IN % 4 == 0) {
            const float4* __restrict__ xv4 = (const float4*)&x[(long)n * IN];
            #pragma unroll
            for (int q = 0; q < IN / 4; ++q) {
                const float4 v = xv4[q];
                acc = fmaf(w[4*q+0], v.x, acc); acc = fmaf(w[4*q+1], v.y, acc);
                acc = fmaf(w[4*q+2], v.z, acc); acc = fmaf(w[4*q+3], v.w, acc);
            }
        } else {
            const float* __restrict__ xv = &x[(long)n * IN];
            #pragma unroll
            for (int j = 0; j < IN; ++j) acc = fmaf(w[j], xv[j], acc);
        }
        out[idx] = acc;
    }
}

// ---------------- decoder layer-1 edge (packed bf16 weights) ---------------
// x2[n, j] = j<64 ? zt[n,j] (bf16) : j==64 ? lower[n] : upper[n]
// Wl[32][138]: [0..63]=zd w, 64=lo_d, 65=up_d, [66..129]=zs w, 130=lo_s,
// 131=up_s, [132..137]=ea w.  zd/zs weights packed bf16, [jp][c] layout.
template<int ITER>
__global__ __launch_bounds__(256)
void dec1_edge_kernel(const __hip_bfloat16* __restrict__ zt,
                      const float* __restrict__ lo, const float* __restrict__ up,
                      const int* __restrict__ ei, int E,
                      const float* __restrict__ ea,   // EA = 6
                      const float* __restrict__ Wl,   // [32, 138]
                      const float* __restrict__ bl,
                      float* __restrict__ out)        // [N2, 32]
{
    __shared__ unsigned sWd[32 * 33];   // zd weight pairs, [jp*33 + c]
    __shared__ unsigned sWs[32 * 33];   // zs weight pairs
    __shared__ float    sWx[32 * 11];   // 10 scalar weights per c, stride 11
    __shared__ float    sB[32];
    for (int i = threadIdx.x; i < 32 * 32; i += 256) {
        const int c = i >> 5, jp = i & 31;
        const float2 d = *(const float2*)&Wl[c * 138 + 2 * jp];
        sWd[jp * 33 + c] = packbf2(d.x, d.y);
        const float2 s2 = *(const float2*)&Wl[c * 138 + 66 + 2 * jp];
        sWs[jp * 33 + c] = packbf2(s2.x, s2.y);
    }
    for (int i = threadIdx.x; i < 32 * 10; i += 256) {
        const int c = i / 10, t = i % 10;
        const int col = (t < 2) ? 64 + t : (t < 4) ? 130 + (t - 2) : 132 + (t - 4);
        sWx[c * 11 + t] = Wl[c * 138 + col];
    }
    if (threadIdx.x < 32) sB[threadIdx.x] = bl[threadIdx.x];
    __syncthreads();

    const int le = threadIdx.x >> 5;
    const int c  = threadIdx.x & 31;
    const float* __restrict__ wx = &sWx[c * 11];
    const int base = blockIdx.x * 8 * ITER;

    #pragma unroll 1
    for (int it = 0; it < ITER; ++it) {
        const int e = base + it * 8 + le;
        if (e >= E) break;
        const int src = ei[e];
        const int dst = ei[E + e];
        float acc0 = sB[c], acc1 = 0.f;
        const uint4* __restrict__ zd4 = (const uint4*)&zt[(long)dst * 64];
        const uint4* __restrict__ zs4 = (const uint4*)&zt[(long)src * 64];
        #pragma unroll
        for (int q = 0; q < 8; ++q) {
            const uint4 u = zd4[q];
            float2 v, w2;
            v = bf2_unpack(u.x); w2 = bf2_unpack(sWd[(4*q+0)*33 + c]);
            acc0 = fmaf(w2.x, v.x, acc0); acc1 = fmaf(w2.y, v.y, acc1);
            v = bf2_unpack(u.y); w2 = bf2_unpack(sWd[(4*q+1)*33 + c]);
            acc0 = fmaf(w2.x, v.x, acc0); acc1 = fmaf(w2.y, v.y, acc1);
            v = bf2_unpack(u.z); w2 = bf2_unpack(sWd[(4*q+2)*33 + c]);
            acc0 = fmaf(w2.x, v.x, acc0); acc1 = fmaf(w2.y, v.y, acc1);
            v = bf2_unpack(u.w); w2 = bf2_unpack(sWd[(4*q+3)*33 + c]);
            acc0 = fmaf(w2.x, v.x, acc0); acc1 = fmaf(w2.y, v.y, acc1);
        }
        #pragma unroll
        for (int q = 0; q < 8; ++q) {
            const uint4 u = zs4[q];
            float2 v, w2;
            v = bf2_unpack(u.x); w2 = bf2_unpack(sWs[(4*q+0)*33 + c]);
            acc0 = fmaf(w2.x, v.x, acc0); acc1 = fmaf(w2.y, v.y, acc1);
            v = bf2_unpack(u.y); w2 = bf2_unpack(sWs[(4*q+1)*33 + c]);
            acc0 = fmaf(w2.x, v.x, acc0); acc1 = fmaf(w2.y, v.y, acc1);
            v = bf2_unpack(u.z); w2 = bf2_unpack(sWs[(4*q+2)*33 + c]);
            acc0 = fmaf(w2.x, v.x, acc0); acc1 = fmaf(w2.y, v.y, acc1);
            v = bf2_unpack(u.w); w2 = bf2_unpack(sWs[(4*q+3)*33 + c]);
            acc0 = fmaf(w2.x, v.x, acc0); acc1 = fmaf(w2.y, v.y, acc1);
        }
        float acc = acc0 + acc1;
        acc = fmaf(wx[0], lo[dst], acc);
        acc = fmaf(wx[1], up[dst], acc);
        acc = fmaf(wx[2], lo[src], acc);
        acc = fmaf(wx[3], up[src], acc);
        const float* __restrict__ eav = &ea[(long)e * 6];
        #pragma unroll
        for (int j = 0; j < 6; ++j) acc = fmaf(wx[4 + j], eav[j], acc);
        acc = acc > 0.f ? acc : 0.01f * acc;
        atomicAdd(&out[(long)dst * 32 + c], acc);
    }
}

template<int ITER>
__global__ __launch_bounds__(256)
void dec1_upsample_kernel(const __hip_bfloat16* __restrict__ zt,
                          const float* __restrict__ lo,
                          const float* __restrict__ up,
                          const float* __restrict__ Wu,  // [32, 66]
                          const float* __restrict__ bu,
                          float* __restrict__ out, int N)
{
    constexpr int IN = 66, INp = 67, OUT = 32;
    __shared__ float sW[OUT * INp];
    __shared__ float sB[OUT];
    for (int i = threadIdx.x; i < OUT * IN; i += 256)
        sW[(i / IN) * INp + (i % IN)] = Wu[i];
    if (threadIdx.x < OUT) sB[threadIdx.x] = bu[threadIdx.x];
    __syncthreads();

    const int total = N * OUT;
    #pragma unroll 1
    for (int it = 0; it < ITER; ++it) {
        const int idx = (blockIdx.x * ITER + it) * 256 + threadIdx.x;
        if (idx >= total) break;
        const int n = idx >> 5, c = idx & 31;
        const float* __restrict__ w = &sW[c * INp];
        const uint4* __restrict__ zn4 = (const uint4*)&zt[(long)n * 64];
        float acc = sB[c];
        #pragma unroll
        for (int q = 0; q < 8; ++q) {
            const uint4 u = zn4[q];
            float2 v;
            v = bf2_unpack(u.x); acc = fmaf(w[8*q+0], v.x, acc); acc = fmaf(w[8*q+1], v.y, acc);
            v = bf2_unpack(u.y); acc = fmaf(w[8*q+2], v.x, acc); acc = fmaf(w[8*q+3], v.y, acc);
            v = bf2_unpack(u.z); acc = fmaf(w[8*q+4], v.x, acc); acc = fmaf(w[8*q+5], v.y, acc);
            v = bf2_unpack(u.w); acc = fmaf(w[8*q+6], v.x, acc); acc = fmaf(w[8*q+7], v.y, acc);
        }
        acc = fmaf(w[64], lo[n], acc);
        acc = fmaf(w[65], up[n], acc);
        out[idx] = acc;
    }
}

// ---------------- temporal blocks ------------------------------------------
// dim-64 (encoder): m = relu(Wt [x_dst|x_src] + bt), mean-aggregate by dst.
// Wt[64][128] packed bf16 pairs, transposed [jp*65 + c]: halves LDS traffic.
template<int ITER>
__global__ __launch_bounds__(256)
void temporal_edge64_kernel(const float* __restrict__ x,
                            const int* __restrict__ ei, int E,
                            const float* __restrict__ Wt,  // [64,128]
                            const float* __restrict__ bt,
                            float* __restrict__ s, float* __restrict__ cnt)
{
    __shared__ unsigned sW[64 * 65];   // 16.6 KB: sW[jp*65+c] = Wt[c][2jp..2jp+1]
    __shared__ float sB[64];
    for (int i = threadIdx.x; i < 64 * 64; i += 256) {
        const int c = i >> 6, jp = i & 63;
        const float2 wv = *(const float2*)&Wt[c * 128 + 2 * jp];
        sW[jp * 65 + c] = packbf2(wv.x, wv.y);
    }
    if (threadIdx.x < 64) sB[threadIdx.x] = bt[threadIdx.x];
    __syncthreads();

    const int le = threadIdx.x >> 6;
    const int c  = threadIdx.x & 63;
    const int base = blockIdx.x * 4 * ITER;

    #pragma unroll 1
    for (int it = 0; it < ITER; ++it) {
        const int e = base + it * 4 + le;
        if (e >= E) break;
        const int src = ei[e];
        const int dst = ei[E + e];
        const float4* __restrict__ xd4 = (const float4*)&x[(long)dst * 64];
        const float4* __restrict__ xs4 = (const float4*)&x[(long)src * 64];
        float a0 = sB[c], a1 = 0.f, a2 = 0.f, a3 = 0.f;
        #pragma unroll
        for (int q = 0; q < 16; ++q) {          // xd: jp = 2q, 2q+1
            const float4 v = xd4[q];
            const float2 w0 = bf2_unpack(sW[(2*q+0) * 65 + c]);
            const float2 w1 = bf2_unpack(sW[(2*q+1) * 65 + c]);
            a0 = fmaf(w0.x, v.x, a0); a1 = fmaf(w0.y, v.y, a1);
            a2 = fmaf(w1.x, v.z, a2); a3 = fmaf(w1.y, v.w, a3);
        }
        #pragma unroll
        for (int q = 0; q < 16; ++q) {          // xs: jp = 32+2q, 32+2q+1
            const float4 v = xs4[q];
            const float2 w0 = bf2_unpack(sW[(32 + 2*q+0) * 65 + c]);
            const float2 w1 = bf2_unpack(sW[(32 + 2*q+1) * 65 + c]);
            a0 = fmaf(w0.x, v.x, a0); a1 = fmaf(w0.y, v.y, a1);
            a2 = fmaf(w1.x, v.z, a2); a3 = fmaf(w1.y, v.w, a3);
        }
        float acc = (a0 + a1) + (a2 + a3);
        acc = fmaxf(acc, 0.f);
        atomicAdd(&s[(long)dst * 64 + c], acc);
        if (c == 0) atomicAdd(&cnt[dst], 1.f);
    }
}

__global__ void temporal_combine64_kernel(const float* __restrict__ s,
                                          const float* __restrict__ cnt,
                                          const float* __restrict__ x,
                                          float* __restrict__ z, int N)
{
    int idx = blockIdx.x * blockDim.x + threadIdx.x;
    if (idx >= N * 64) return;
    const int n = idx >> 6;
    z[idx] = s[idx] / fmaxf(cnt[n], 1.f) + x[idx];
}

__global__ void temporal_edge1_kernel(const float* __restrict__ x,
                                      const int* __restrict__ ei, int E,
                                      const float* __restrict__ Wt,
                                      const float* __restrict__ bt,
                                      float* __restrict__ s, float* __restrict__ cnt)
{
    int e = blockIdx.x * blockDim.x + threadIdx.x;
    if (e >= E) return;
    const int src = ei[e];
    const int dst = ei[E + e];
    float m = Wt[0] * x[dst] + Wt[1] * x[src] + bt[0];
    m = fmaxf(m, 0.f);
    atomicAdd(&s[dst], m);
    atomicAdd(&cnt[dst], 1.f);
}

// ---------------- transform GEMM (bf16 MFMA, cast on stage) ----------------
__global__ __launch_bounds__(256)
void gemm_mfma_tanh_kernel(const float* __restrict__ A,
                           const float* __restrict__ W,
                           const float* __restrict__ bias,
                           __hip_bfloat16* __restrict__ out)
{
    constexpr int BM = 128, LDP = 40;   // ushort pitch: 80B rows, 2-way banks
    __shared__ ushort sA[BM * LDP];
    __shared__ ushort sB[BM * LDP];
    const int tid  = threadIdx.x;
    const int lane = tid & 63;
    const int wid  = tid >> 6;
    const int wr = wid >> 1, wc = wid & 1;
    const long bm = (long)blockIdx.y * BM;
    const long bn = (long)blockIdx.x * BM;

    const int sr = tid >> 1;      // 0..127: staged tile row
    const int sh = tid & 1;       // 0/1: which 16-element k-half
    const float* __restrict__ gA = &A[(bm + sr) * kK + sh * 16];
    const float* __restrict__ gB = &W[(bn + sr) * kK + sh * 16];
    ushort* dA = &sA[sr * LDP + sh * 16];
    ushort* dB = &sB[sr * LDP + sh * 16];

    f32x4 acc[4][4] = {};
    const int g    = lane >> 4;   // k-group (8 bf16 each)
    const int rsel = lane & 15;

    for (int k0 = 0; k0 < kK; k0 += 32) {
        const float4 a0 = *(const float4*)(gA + k0 + 0);
        const float4 a1 = *(const float4*)(gA + k0 + 4);
        const float4 a2 = *(const float4*)(gA + k0 + 8);
        const float4 a3 = *(const float4*)(gA + k0 + 12);
        const float4 b0 = *(const float4*)(gB + k0 + 0);
        const float4 b1 = *(const float4*)(gB + k0 + 4);
        const float4 b2 = *(const float4*)(gB + k0 + 8);
        const float4 b3 = *(const float4*)(gB + k0 + 12);
        __syncthreads();                      // previous tile fully consumed
        pack8(dA, a0, a1); pack8(dA + 8, a2, a3);
        pack8(dB, b0, b1); pack8(dB + 8, b2, b3);
        __syncthreads();

        bf16x8 af[4], bfm[4];
        #pragma unroll
        for (int m = 0; m < 4; ++m)
            af[m] = *(const bf16x8*)&sA[(wr * 64 + m * 16 + rsel) * LDP + g * 8];
        #pragma unroll
        for (int n = 0; n < 4; ++n)
            bfm[n] = *(const bf16x8*)&sB[(wc * 64 + n * 16 + rsel) * LDP + g * 8];
        #pragma unroll
        for (int m = 0; m < 4; ++m)
            #pragma unroll
            for (int n = 0; n < 4; ++n)
                acc[m][n] = __builtin_amdgcn_mfma_f32_16x16x32_bf16(
                    af[m], bfm[n], acc[m][n], 0, 0, 0);
    }

    // epilogue: D frag col = lane&15, row = (lane>>4)*4 + reg
    const long colb = bn + wc * 64 + (lane & 15);
    const long rowb = bm + wr * 64 + (lane >> 4) * 4;
    #pragma unroll
    for (int n = 0; n < 4; ++n) {
        const long col = colb + n * 16;
        const float bs = bias[col];
        #pragma unroll
        for (int m = 0; m < 4; ++m) {
            #pragma unroll
            for (int r = 0; r < 4; ++r) {
                const float v = tanhf(acc[m][n][r] + bs);
                out[(rowb + m * 16 + r) * kN + col] = __float2bfloat16(v);
            }
        }
    }
}

// ---------------- final: tanh(temporal) -> affine to joint range -----------
__global__ void final_kernel(const float* __restrict__ s,
                             const float* __restrict__ cnt,
                             const float* __restrict__ d3,
                             const float* __restrict__ lo,
                             const float* __restrict__ up,
                             float* __restrict__ out, int N)
{
    int i = blockIdx.x * blockDim.x + threadIdx.x;
    if (i >= N) return;
    const float t = s[i] / fmaxf(cnt[i], 1.f) + d3[i];
    const float o = tanhf(t);
    out[i] = lo[i] + (up[i] - lo[i]) * (o + 1.f) * 0.5f;
}

// ---------------------------------------------------------------------------
extern "C" void kernel_launch(void* const* d_in, const int* in_sizes, int n_in,
                              void* d_out, int out_size, void* d_ws, size_t ws_size,
                              hipStream_t stream)
{
    const float* x     = (const float*)d_in[0];
    const int*   ei1   = (const int*)  d_in[1];
    const float* ea1   = (const float*)d_in[2];
    const int*   tei1  = (const int*)  d_in[3];
    const float* lower = (const float*)d_in[4];
    const float* upper = (const float*)d_in[5];
    const int*   ei2   = (const int*)  d_in[6];
    const float* ea2   = (const float*)d_in[7];
    const int*   tei2  = (const int*)  d_in[8];
    const float* We1_l = (const float*)d_in[9];  const float* be1_l = (const float*)d_in[10];
    const float* We1_u = (const float*)d_in[11]; const float* be1_u = (const float*)d_in[12];
    const float* We2_l = (const float*)d_in[13]; const float* be2_l = (const float*)d_in[14];
    const float* We2_u = (const float*)d_in[15]; const float* be2_u = (const float*)d_in[16];
    const float* We3_l = (const float*)d_in[17]; const float* be3_l = (const float*)d_in[18];
    const float* We3_u = (const float*)d_in[19]; const float* be3_u = (const float*)d_in[20];
    const float* Wt1   = (const float*)d_in[21]; const float* bt1   = (const float*)d_in[22];
    const float* W_tr  = (const float*)d_in[23]; const float* b_tr  = (const float*)d_in[24];
    const float* Wd1_l = (const float*)d_in[25]; const float* bd1_l = (const float*)d_in[26];
    const float* Wd1_u = (const float*)d_in[27]; const float* bd1_u = (const float*)d_in[28];
    const float* Wd2_l = (const float*)d_in[29]; const float* bd2_l = (const float*)d_in[30];
    const float* Wd2_u = (const float*)d_in[31]; const float* bd2_u = (const float*)d_in[32];
    const float* Wd3_l = (const float*)d_in[33]; const float* bd3_l = (const float*)d_in[34];
    const float* Wd3_u = (const float*)d_in[35]; const float* bd3_u = (const float*)d_in[36];
    const float* Wt2   = (const float*)d_in[37]; const float* bt2   = (const float*)d_in[38];

    // workspace layout (bytes):
    //   bufA: 117,440,512   (holds h1/h3/zt(bf16)/d2)
    //   bufB: 117,440,512   (holds h2/s1/z/d1/d3)
    //   bufC:   7,340,032   (holds cnt1 | s2+cnt2)
    char* ws = (char*)d_ws;
    float* bufA = (float*)ws;
    float* bufB = (float*)(ws + 117440512);
    float* bufC = (float*)(ws + 234881024);
    __hip_bfloat16* zt = (__hip_bfloat16*)bufA;

    const int TPB = 256;
    auto cdiv = [](long a, long b) { return (int)((a + b - 1) / b); };

    // ---- encoder spatial 1: x[6] -> h1[16]  (h1 = bufA)
    upsample_kernel<6, 16, 8><<<cdiv((long)kN1 * 16, 2048), TPB, 0, stream>>>(
        x, kN1, We1_u, be1_u, bufA);
    spatial_edge_kernel<6, 3, 16, 256, 4><<<cdiv(kE1, 64), TPB, 0, stream>>>(
        x, ei1, kE1, ea1, We1_l, be1_l, bufA);

    // ---- encoder spatial 2: h1[16] -> h2[32]  (h2 = bufB)
    upsample_kernel<16, 32, 8><<<cdiv((long)kN1 * 32, 2048), TPB, 0, stream>>>(
        bufA, kN1, We2_u, be2_u, bufB);
    spatial_edge_kernel<16, 3, 32, 256, 4><<<cdiv(kE1, 32), TPB, 0, stream>>>(
        bufA, ei1, kE1, ea1, We2_l, be2_l, bufB);

    // ---- encoder spatial 3: h2[32] -> h3[64]  (h3 = bufA)
    upsample_kernel<32, 64, 8><<<cdiv((long)kN1 * 64, 2048), TPB, 0, stream>>>(
        bufB, kN1, We3_u, be3_u, bufA);
    spatial_edge_kernel<32, 3, 64, 256, 8><<<cdiv(kE1, 32), TPB, 0, stream>>>(
        bufB, ei1, kE1, ea1, We3_l, be3_l, bufA);

    // ---- encoder temporal (dim 64): s1 = bufB, cnt1 = bufC, z in-place bufB
    hipMemsetAsync(bufB, 0, (size_t)kN1 * 64 * sizeof(float), stream);
    hipMemsetAsync(bufC, 0, (size_t)kN1 * sizeof(float), stream);
    temporal_edge64_kernel<32><<<cdiv(kN1, 128), 256, 0, stream>>>(
        bufA, tei1, kN1, Wt1, bt1, bufB, bufC);
    temporal_combine64_kernel<<<cdiv((long)kN1 * 64, TPB), TPB, 0, stream>>>(
        bufB, bufC, bufA, bufB, kN1);

    // ---- transform GEMM: z(bufB [65536,384] f32) @ W_tr^T -> tanh -> zt bf16
    {
        dim3 grid(kN / 128, kM / 128);
        gemm_mfma_tanh_kernel<<<grid, 256, 0, stream>>>(bufB, W_tr, b_tr, zt);
    }

    // ---- decoder spatial 1: x2[66] (virtual) -> d1[32]  (d1 = bufB)
    dec1_upsample_kernel<8><<<cdiv((long)kN2 * 32, 2048), TPB, 0, stream>>>(
        zt, lower, upper, Wd1_u, bd1_u, bufB, kN2);
    dec1_edge_kernel<8><<<cdiv(kE2, 64), TPB, 0, stream>>>(
        zt, lower, upper, ei2, kE2, ea2, Wd1_l, bd1_l, bufB);

    // ---- decoder spatial 2: d1[32] -> d2[16]  (d2 = bufA as f32)
    float* d2 = (float*)bufA;
    upsample_kernel<32, 16, 8><<<cdiv((long)kN2 * 16, 2048), TPB, 0, stream>>>(
        bufB, kN2, Wd2_u, bd2_u, d2);
    spatial_edge_kernel<32, 6, 16, 256, 4><<<cdiv(kE2, 64), TPB, 0, stream>>>(
        bufB, ei2, kE2, ea2, Wd2_l, bd2_l, d2);

    // ---- decoder spatial 3: d2[16] -> d3[1]  (d3 = bufB)
    float* d3 = bufB;
    upsample_kernel<16, 1, 8><<<cdiv(kN2, 2048), TPB, 0, stream>>>(
        d2, kN2, Wd3_u, bd3_u, d3);
    spatial_edge_kernel<16, 6, 1, 256, 1><<<cdiv(kE2, 256), TPB, 0, stream>>>(
        d2, ei2, kE2, ea2, Wd3_l, bd3_l, d3);

    // ---- decoder temporal (dim 1) + final affine
    hipMemsetAsync(bufC, 0, (size_t)2 * kN2 * sizeof(float), stream);
    temporal_edge1_kernel<<<cdiv(kN2, TPB), TPB, 0, stream>>>(
        d3, tei2, kN2, Wt2, bt2, bufC, bufC + kN2);
    final_kernel<<<cdiv(kN2, TPB), TPB, 0, stream>>>(
        bufC, bufC + kN2, d3, lower, upper, (float*)d_out, kN2);
}

// Round 6
// 1567.760 us; speedup vs baseline: 3.0982x; 1.2796x over previous
//
#include <hip/hip_runtime.h>
#include <hip/hip_bf16.h>

// ---------------------------------------------------------------------------
// ArmNet forward. Round 6: temporal64 + dec1 edge-MLPs reformulated as fused
// gather -> bf16 MFMA -> scatter GEMMs (block-level staging gives ~1000s of
// outstanding gather loads vs ~2 in the per-wave MLP form, which round-5
// counters showed to be latency-bound). Rest unchanged from round 5.
// ---------------------------------------------------------------------------

constexpr int kN1 = 393216;   // encoder nodes
constexpr int kE1 = 327680;   // encoder edges
constexpr int kN2 = 917504;   // decoder nodes
constexpr int kE2 = 851968;   // decoder edges
constexpr int kM  = 65536;    // B*PERIOD (transform GEMM rows)
constexpr int kK  = 384;      // transform K
constexpr int kN  = 896;      // transform N (14*64)

typedef __attribute__((ext_vector_type(8))) short bf16x8;
typedef __attribute__((ext_vector_type(4))) float f32x4;

__device__ inline float2 bf2_unpack(unsigned u) {
    union { unsigned i; float f; } a, b;
    a.i = u << 16;           // element 2j   (low half)
    b.i = u & 0xffff0000u;   // element 2j+1 (high half)
    return make_float2(a.f, b.f);
}

__device__ inline ushort f2bf(float f) {   // RNE f32 -> bf16 (finite inputs)
    union { float f; unsigned u; } x; x.f = f;
    unsigned r = x.u + 0x7fffu + ((x.u >> 16) & 1u);
    return (ushort)(r >> 16);
}

__device__ inline void pack8(ushort* d, float4 u, float4 v) {
    bf16x8 p;
    p[0] = (short)f2bf(u.x); p[1] = (short)f2bf(u.y);
    p[2] = (short)f2bf(u.z); p[3] = (short)f2bf(u.w);
    p[4] = (short)f2bf(v.x); p[5] = (short)f2bf(v.y);
    p[6] = (short)f2bf(v.z); p[7] = (short)f2bf(v.w);
    *(bf16x8*)d = p;
}

// ---------------- generic spatial edge kernel (small layers) ---------------
template<int IN, int EA, int OUT, int TPB, int ITER>
__global__ __launch_bounds__(TPB)
void spatial_edge_kernel(const float* __restrict__ x,
                         const int* __restrict__ ei, int E,
                         const float* __restrict__ ea,
                         const float* __restrict__ Wl,
                         const float* __restrict__ bl,
                         float* __restrict__ out)
{
    constexpr int Z  = 2 * IN + EA;
    constexpr int Zp = (Z % 2 == 0) ? Z + 1 : Z;   // odd stride: conflict-free
    constexpr int EPB = TPB / OUT;
    static_assert(TPB % OUT == 0, "TPB % OUT");
    __shared__ float sW[OUT * Zp];
    __shared__ float sB[OUT];
    for (int i = threadIdx.x; i < OUT * Z; i += TPB)
        sW[(i / Z) * Zp + (i % Z)] = Wl[i];
    for (int i = threadIdx.x; i < OUT; i += TPB) sB[i] = bl[i];
    __syncthreads();

    const int le = threadIdx.x / OUT;
    const int c  = threadIdx.x % OUT;
    const float* __restrict__ w = &sW[c * Zp];
    const int base = blockIdx.x * EPB * ITER;

    #pragma unroll 1
    for (int it = 0; it < ITER; ++it) {
        const int e = base + it * EPB + le;
        if (e >= E) break;
        const int src = ei[e];
        const int dst = ei[E + e];
        float acc = sB[c];
        if constexpr (IN % 4 == 0) {
            const float4* __restrict__ xd4 = (const float4*)&x[(long)dst * IN];
            const float4* __restrict__ xs4 = (const float4*)&x[(long)src * IN];
            #pragma unroll
            for (int q = 0; q < IN / 4; ++q) {
                const float4 v = xd4[q];
                acc = fmaf(w[4*q+0], v.x, acc); acc = fmaf(w[4*q+1], v.y, acc);
                acc = fmaf(w[4*q+2], v.z, acc); acc = fmaf(w[4*q+3], v.w, acc);
            }
            #pragma unroll
            for (int q = 0; q < IN / 4; ++q) {
                const float4 v = xs4[q];
                acc = fmaf(w[IN+4*q+0], v.x, acc); acc = fmaf(w[IN+4*q+1], v.y, acc);
                acc = fmaf(w[IN+4*q+2], v.z, acc); acc = fmaf(w[IN+4*q+3], v.w, acc);
            }
        } else {
            const float* __restrict__ xd = &x[(long)dst * IN];
            const float* __restrict__ xs = &x[(long)src * IN];
            #pragma unroll
            for (int j = 0; j < IN; ++j) acc = fmaf(w[j], xd[j], acc);
            #pragma unroll
            for (int j = 0; j < IN; ++j) acc = fmaf(w[IN + j], xs[j], acc);
        }
        const float* __restrict__ eav = &ea[(long)e * EA];
        #pragma unroll
        for (int j = 0; j < EA; ++j) acc = fmaf(w[2 * IN + j], eav[j], acc);
        acc = acc > 0.f ? acc : 0.01f * acc;     // leaky_relu(0.01)
        atomicAdd(&out[(long)dst * OUT + c], acc);
    }
}

// ---------------- generic upsample (residual linear) -----------------------
template<int IN, int OUT, int ITER>
__global__ __launch_bounds__(256)
void upsample_kernel(const float* __restrict__ x, int N,
                     const float* __restrict__ Wu,
                     const float* __restrict__ bu,
                     float* __restrict__ out)
{
    constexpr int INp = (IN % 2 == 0) ? IN + 1 : IN;
    __shared__ float sW[OUT * INp];
    __shared__ float sB[OUT];
    for (int i = threadIdx.x; i < OUT * IN; i += 256)
        sW[(i / IN) * INp + (i % IN)] = Wu[i];
    for (int i = threadIdx.x; i < OUT; i += 256) sB[i] = bu[i];
    __syncthreads();

    const int total = N * OUT;
    #pragma unroll 1
    for (int it = 0; it < ITER; ++it) {
        const int idx = (blockIdx.x * ITER + it) * 256 + threadIdx.x;
        if (idx >= total) break;
        const int n = idx / OUT, c = idx % OUT;
        const float* __restrict__ w = &sW[c * INp];
        float acc = sB[c];
        if constexpr (IN % 4 == 0) {
            const float4* __restrict__ xv4 = (const float4*)&x[(long)n * IN];
            #pragma unroll
            for (int q = 0; q < IN / 4; ++q) {
                const float4 v = xv4[q];
                acc = fmaf(w[4*q+0], v.x, acc); acc = fmaf(w[4*q+1], v.y, acc);
                acc = fmaf(w[4*q+2], v.z, acc); acc = fmaf(w[4*q+3], v.w, acc);
            }
        } else {
            const float* __restrict__ xv = &x[(long)n * IN];
            #pragma unroll
            for (int j = 0; j < IN; ++j) acc = fmaf(w[j], xv[j], acc);
        }
        out[idx] = acc;
    }
}

template<int ITER>
__global__ __launch_bounds__(256)
void dec1_upsample_kernel(const __hip_bfloat16* __restrict__ zt,
                          const float* __restrict__ lo,
                          const float* __restrict__ up,
                          const float* __restrict__ Wu,  // [32, 66]
                          const float* __restrict__ bu,
                          float* __restrict__ out, int N)
{
    constexpr int IN = 66, INp = 67, OUT = 32;
    __shared__ float sW[OUT * INp];
    __shared__ float sB[OUT];
    for (int i = threadIdx.x; i < OUT * IN; i += 256)
        sW[(i / IN) * INp + (i % IN)] = Wu[i];
    if (threadIdx.x < OUT) sB[threadIdx.x] = bu[threadIdx.x];
    __syncthreads();

    const int total = N * OUT;
    #pragma unroll 1
    for (int it = 0; it < ITER; ++it) {
        const int idx = (blockIdx.x * ITER + it) * 256 + threadIdx.x;
        if (idx >= total) break;
        const int n = idx >> 5, c = idx & 31;
        const float* __restrict__ w = &sW[c * INp];
        const uint4* __restrict__ zn4 = (const uint4*)&zt[(long)n * 64];
        float acc = sB[c];
        #pragma unroll
        for (int q = 0; q < 8; ++q) {
            const uint4 u = zn4[q];
            float2 v;
            v = bf2_unpack(u.x); acc = fmaf(w[8*q+0], v.x, acc); acc = fmaf(w[8*q+1], v.y, acc);
            v = bf2_unpack(u.y); acc = fmaf(w[8*q+2], v.x, acc); acc = fmaf(w[8*q+3], v.y, acc);
            v = bf2_unpack(u.z); acc = fmaf(w[8*q+4], v.x, acc); acc = fmaf(w[8*q+5], v.y, acc);
            v = bf2_unpack(u.w); acc = fmaf(w[8*q+6], v.x, acc); acc = fmaf(w[8*q+7], v.y, acc);
        }
        acc = fmaf(w[64], lo[n], acc);
        acc = fmaf(w[65], up[n], acc);
        out[idx] = acc;
    }
}

// ---------------- temporal (dim 64) as fused gather-MFMA-scatter GEMM ------
// A row r = [ x[dst[e0+r]] | x[src[e0+r]] ] (128 f32 -> bf16), B = Wt[64][128].
// m = relu(A B^T + bt); s[dst] += m; cnt[dst] += 1.
__global__ __launch_bounds__(256)
void temporal_gemm_kernel(const float* __restrict__ x,
                          const int* __restrict__ ei, int E,
                          const float* __restrict__ Wt,  // [64,128]
                          const float* __restrict__ bt,
                          float* __restrict__ s, float* __restrict__ cnt)
{
    constexpr int MT = 128, LDA = 136, LDB = 136;
    __shared__ ushort sA[MT * LDA];     // 34816 B
    __shared__ ushort sB[64 * LDB];     // 17408 B
    __shared__ float  sBias[64];
    __shared__ int    sDst[MT];

    const int tid = threadIdx.x;
    const int e0  = blockIdx.x * MT;

    // stage B (Wt) + bias
    for (int i = tid; i < 64 * 32; i += 256) {
        const int ch = i >> 5, q = i & 31;
        const float4 v = *(const float4*)&Wt[ch * 128 + q * 4];
        ushort* d = &sB[ch * LDB + q * 4];
        d[0] = f2bf(v.x); d[1] = f2bf(v.y); d[2] = f2bf(v.z); d[3] = f2bf(v.w);
    }
    if (tid < 64) sBias[tid] = bt[tid];

    // stage A: 2 threads per edge row (sh=0: dst half, sh=1: src half)
    {
        const int r  = tid >> 1, sh = tid & 1;
        const int e  = e0 + r;
        const int node = sh ? ei[e] : ei[E + e];
        const float4* __restrict__ xr = (const float4*)&x[(long)node * 64];
        ushort* d = &sA[r * LDA + sh * 64];
        #pragma unroll
        for (int q = 0; q < 16; q += 2)
            pack8(d + q * 4, xr[q], xr[q + 1]);
        if (sh == 0) {
            sDst[r] = node;
            atomicAdd(&cnt[node], 1.f);
        }
    }
    __syncthreads();

    // MFMA: wave wid owns edge rows [wid*32, wid*32+32)
    const int lane = tid & 63, wid = tid >> 6;
    const int g = lane >> 4, rsel = lane & 15;
    f32x4 acc[2][4] = {};
    #pragma unroll
    for (int ks = 0; ks < 4; ++ks) {
        bf16x8 a_[2], b_[4];
        #pragma unroll
        for (int m = 0; m < 2; ++m)
            a_[m] = *(const bf16x8*)&sA[(wid*32 + m*16 + rsel) * LDA + ks*32 + g*8];
        #pragma unroll
        for (int n = 0; n < 4; ++n)
            b_[n] = *(const bf16x8*)&sB[(n*16 + rsel) * LDB + ks*32 + g*8];
        #pragma unroll
        for (int m = 0; m < 2; ++m)
            #pragma unroll
            for (int n = 0; n < 4; ++n)
                acc[m][n] = __builtin_amdgcn_mfma_f32_16x16x32_bf16(
                    a_[m], b_[n], acc[m][n], 0, 0, 0);
    }

    // epilogue: row = wid*32 + m*16 + (lane>>4)*4 + rr ; col = n*16 + rsel
    #pragma unroll
    for (int m = 0; m < 2; ++m) {
        #pragma unroll
        for (int rr = 0; rr < 4; ++rr) {
            const int row = wid*32 + m*16 + g*4 + rr;
            const long dst = sDst[row];
            #pragma unroll
            for (int n = 0; n < 4; ++n) {
                const int col = n*16 + rsel;
                const float v = fmaxf(acc[m][n][rr] + sBias[col], 0.f);
                atomicAdd(&s[dst * 64 + col], v);
            }
        }
    }
}

// ---------------- decoder layer-1 as fused gather-MFMA-scatter GEMM --------
// K layout (160, zero-padded): [0..63]=zt[dst], 64=lo_d, 65=up_d,
// [66..129]=zt[src], 130=lo_s, 131=up_s, [132..137]=ea, [138..159]=0.
// m = leaky_relu(A Wd1_l^T + bd1_l); out[dst] += m  (out pre-filled).
__global__ __launch_bounds__(256)
void dec1_gemm_kernel(const __hip_bfloat16* __restrict__ zt,
                      const float* __restrict__ lo, const float* __restrict__ up,
                      const int* __restrict__ ei, int E,
                      const float* __restrict__ ea,   // [E,6]
                      const float* __restrict__ Wl,   // [32,138]
                      const float* __restrict__ bl,
                      float* __restrict__ out)        // [N2,32]
{
    constexpr int MT = 128, LDA = 168, LDB = 168;
    __shared__ ushort sA[MT * LDA];     // 43008 B
    __shared__ ushort sB[32 * LDB];     // 10752 B
    __shared__ float  sBias[32];
    __shared__ int    sDst[MT];

    const int tid = threadIdx.x;
    const int e0  = blockIdx.x * MT;

    // stage B (Wl) + zero pad + bias
    for (int i = tid; i < 32 * 160; i += 256) {
        const int ch = i / 160, j = i % 160;
        sB[ch * LDB + j] = (j < 138) ? f2bf(Wl[ch * 138 + j]) : (ushort)0;
    }
    if (tid < 32) sBias[tid] = bl[tid];

    // stage A: 2 threads per edge row
    {
        const int r  = tid >> 1, sh = tid & 1;
        const int e  = e0 + r;
        const int node = sh ? ei[e] : ei[E + e];
        ushort* d = &sA[r * LDA + sh * 66];
        uint* d32 = (uint*)d;                     // 4B-aligned
        const uint4* __restrict__ zr = (const uint4*)&zt[(long)node * 64];
        #pragma unroll
        for (int q = 0; q < 8; ++q) {
            const uint4 u = zr[q];
            d32[4*q+0] = u.x; d32[4*q+1] = u.y; d32[4*q+2] = u.z; d32[4*q+3] = u.w;
        }
        d[64] = f2bf(lo[node]);
        d[65] = f2bf(up[node]);
        if (sh) {
            const float* __restrict__ eav = &ea[(long)e * 6];
            #pragma unroll
            for (int j = 0; j < 6; ++j) d[66 + j] = f2bf(eav[j]);
            #pragma unroll
            for (int j = 72; j < 94; ++j) d[j] = 0;   // k 138..159
        } else {
            sDst[r] = node;
        }
    }
    __syncthreads();

    const int lane = tid & 63, wid = tid >> 6;
    const int g = lane >> 4, rsel = lane & 15;
    f32x4 acc[2][2] = {};
    #pragma unroll
    for (int ks = 0; ks < 5; ++ks) {
        bf16x8 a_[2], b_[2];
        #pragma unroll
        for (int m = 0; m < 2; ++m)
            a_[m] = *(const bf16x8*)&sA[(wid*32 + m*16 + rsel) * LDA + ks*32 + g*8];
        #pragma unroll
        for (int n = 0; n < 2; ++n)
            b_[n] = *(const bf16x8*)&sB[(n*16 + rsel) * LDB + ks*32 + g*8];
        #pragma unroll
        for (int m = 0; m < 2; ++m)
            #pragma unroll
            for (int n = 0; n < 2; ++n)
                acc[m][n] = __builtin_amdgcn_mfma_f32_16x16x32_bf16(
                    a_[m], b_[n], acc[m][n], 0, 0, 0);
    }

    #pragma unroll
    for (int m = 0; m < 2; ++m) {
        #pragma unroll
        for (int rr = 0; rr < 4; ++rr) {
            const int row = wid*32 + m*16 + g*4 + rr;
            const long dst = sDst[row];
            #pragma unroll
            for (int n = 0; n < 2; ++n) {
                const int col = n*16 + rsel;
                float v = acc[m][n][rr] + sBias[col];
                v = v > 0.f ? v : 0.01f * v;
                atomicAdd(&out[dst * 32 + col], v);
            }
        }
    }
}

// ---------------- temporal combine / dim-1 temporal ------------------------
__global__ void temporal_combine64_kernel(const float* __restrict__ s,
                                          const float* __restrict__ cnt,
                                          const float* __restrict__ x,
                                          float* __restrict__ z, int N)
{
    int idx = blockIdx.x * blockDim.x + threadIdx.x;
    if (idx >= N * 64) return;
    const int n = idx >> 6;
    z[idx] = s[idx] / fmaxf(cnt[n], 1.f) + x[idx];
}

__global__ void temporal_edge1_kernel(const float* __restrict__ x,
                                      const int* __restrict__ ei, int E,
                                      const float* __restrict__ Wt,
                                      const float* __restrict__ bt,
                                      float* __restrict__ s, float* __restrict__ cnt)
{
    int e = blockIdx.x * blockDim.x + threadIdx.x;
    if (e >= E) return;
    const int src = ei[e];
    const int dst = ei[E + e];
    float m = Wt[0] * x[dst] + Wt[1] * x[src] + bt[0];
    m = fmaxf(m, 0.f);
    atomicAdd(&s[dst], m);
    atomicAdd(&cnt[dst], 1.f);
}

// ---------------- transform GEMM (bf16 MFMA, cast on stage) ----------------
__global__ __launch_bounds__(256)
void gemm_mfma_tanh_kernel(const float* __restrict__ A,
                           const float* __restrict__ W,
                           const float* __restrict__ bias,
                           __hip_bfloat16* __restrict__ out)
{
    constexpr int BM = 128, LDP = 40;   // ushort pitch: 80B rows, 2-way banks
    __shared__ ushort sA[BM * LDP];
    __shared__ ushort sB[BM * LDP];
    const int tid  = threadIdx.x;
    const int lane = tid & 63;
    const int wid  = tid >> 6;
    const int wr = wid >> 1, wc = wid & 1;
    const long bm = (long)blockIdx.y * BM;
    const long bn = (long)blockIdx.x * BM;

    const int sr = tid >> 1;      // 0..127: staged tile row
    const int sh = tid & 1;       // 0/1: which 16-element k-half
    const float* __restrict__ gA = &A[(bm + sr) * kK + sh * 16];
    const float* __restrict__ gB = &W[(bn + sr) * kK + sh * 16];
    ushort* dA = &sA[sr * LDP + sh * 16];
    ushort* dB = &sB[sr * LDP + sh * 16];

    f32x4 acc[4][4] = {};
    const int g    = lane >> 4;   // k-group (8 bf16 each)
    const int rsel = lane & 15;

    for (int k0 = 0; k0 < kK; k0 += 32) {
        const float4 a0 = *(const float4*)(gA + k0 + 0);
        const float4 a1 = *(const float4*)(gA + k0 + 4);
        const float4 a2 = *(const float4*)(gA + k0 + 8);
        const float4 a3 = *(const float4*)(gA + k0 + 12);
        const float4 b0 = *(const float4*)(gB + k0 + 0);
        const float4 b1 = *(const float4*)(gB + k0 + 4);
        const float4 b2 = *(const float4*)(gB + k0 + 8);
        const float4 b3 = *(const float4*)(gB + k0 + 12);
        __syncthreads();                      // previous tile fully consumed
        pack8(dA, a0, a1); pack8(dA + 8, a2, a3);
        pack8(dB, b0, b1); pack8(dB + 8, b2, b3);
        __syncthreads();

        bf16x8 af[4], bfm[4];
        #pragma unroll
        for (int m = 0; m < 4; ++m)
            af[m] = *(const bf16x8*)&sA[(wr * 64 + m * 16 + rsel) * LDP + g * 8];
        #pragma unroll
        for (int n = 0; n < 4; ++n)
            bfm[n] = *(const bf16x8*)&sB[(wc * 64 + n * 16 + rsel) * LDP + g * 8];
        #pragma unroll
        for (int m = 0; m < 4; ++m)
            #pragma unroll
            for (int n = 0; n < 4; ++n)
                acc[m][n] = __builtin_amdgcn_mfma_f32_16x16x32_bf16(
                    af[m], bfm[n], acc[m][n], 0, 0, 0);
    }

    // epilogue: D frag col = lane&15, row = (lane>>4)*4 + reg
    const long colb = bn + wc * 64 + (lane & 15);
    const long rowb = bm + wr * 64 + (lane >> 4) * 4;
    #pragma unroll
    for (int n = 0; n < 4; ++n) {
        const long col = colb + n * 16;
        const float bs = bias[col];
        #pragma unroll
        for (int m = 0; m < 4; ++m) {
            #pragma unroll
            for (int r = 0; r < 4; ++r) {
                const float v = tanhf(acc[m][n][r] + bs);
                out[(rowb + m * 16 + r) * kN + col] = __float2bfloat16(v);
            }
        }
    }
}

// ---------------- final: tanh(temporal) -> affine to joint range -----------
__global__ void final_kernel(const float* __restrict__ s,
                             const float* __restrict__ cnt,
                             const float* __restrict__ d3,
                             const float* __restrict__ lo,
                             const float* __restrict__ up,
                             float* __restrict__ out, int N)
{
    int i = blockIdx.x * blockDim.x + threadIdx.x;
    if (i >= N) return;
    const float t = s[i] / fmaxf(cnt[i], 1.f) + d3[i];
    const float o = tanhf(t);
    out[i] = lo[i] + (up[i] - lo[i]) * (o + 1.f) * 0.5f;
}

// ---------------------------------------------------------------------------
extern "C" void kernel_launch(void* const* d_in, const int* in_sizes, int n_in,
                              void* d_out, int out_size, void* d_ws, size_t ws_size,
                              hipStream_t stream)
{
    const float* x     = (const float*)d_in[0];
    const int*   ei1   = (const int*)  d_in[1];
    const float* ea1   = (const float*)d_in[2];
    const int*   tei1  = (const int*)  d_in[3];
    const float* lower = (const float*)d_in[4];
    const float* upper = (const float*)d_in[5];
    const int*   ei2   = (const int*)  d_in[6];
    const float* ea2   = (const float*)d_in[7];
    const int*   tei2  = (const int*)  d_in[8];
    const float* We1_l = (const float*)d_in[9];  const float* be1_l = (const float*)d_in[10];
    const float* We1_u = (const float*)d_in[11]; const float* be1_u = (const float*)d_in[12];
    const float* We2_l = (const float*)d_in[13]; const float* be2_l = (const float*)d_in[14];
    const float* We2_u = (const float*)d_in[15]; const float* be2_u = (const float*)d_in[16];
    const float* We3_l = (const float*)d_in[17]; const float* be3_l = (const float*)d_in[18];
    const float* We3_u = (const float*)d_in[19]; const float* be3_u = (const float*)d_in[20];
    const float* Wt1   = (const float*)d_in[21]; const float* bt1   = (const float*)d_in[22];
    const float* W_tr  = (const float*)d_in[23]; const float* b_tr  = (const float*)d_in[24];
    const float* Wd1_l = (const float*)d_in[25]; const float* bd1_l = (const float*)d_in[26];
    const float* Wd1_u = (const float*)d_in[27]; const float* bd1_u = (const float*)d_in[28];
    const float* Wd2_l = (const float*)d_in[29]; const float* bd2_l = (const float*)d_in[30];
    const float* Wd2_u = (const float*)d_in[31]; const float* bd2_u = (const float*)d_in[32];
    const float* Wd3_l = (const float*)d_in[33]; const float* bd3_l = (const float*)d_in[34];
    const float* Wd3_u = (const float*)d_in[35]; const float* bd3_u = (const float*)d_in[36];
    const float* Wt2   = (const float*)d_in[37]; const float* bt2   = (const float*)d_in[38];

    // workspace layout (bytes):
    //   bufA: 117,440,512   (holds h1/h3/zt(bf16)/d2)
    //   bufB: 117,440,512   (holds h2/s1/z/d1/d3)
    //   bufC:   7,340,032   (holds cnt1 | s2+cnt2)
    char* ws = (char*)d_ws;
    float* bufA = (float*)ws;
    float* bufB = (float*)(ws + 117440512);
    float* bufC = (float*)(ws + 234881024);
    __hip_bfloat16* zt = (__hip_bfloat16*)bufA;

    const int TPB = 256;
    auto cdiv = [](long a, long b) { return (int)((a + b - 1) / b); };

    // ---- encoder spatial 1: x[6] -> h1[16]  (h1 = bufA)
    upsample_kernel<6, 16, 8><<<cdiv((long)kN1 * 16, 2048), TPB, 0, stream>>>(
        x, kN1, We1_u, be1_u, bufA);
    spatial_edge_kernel<6, 3, 16, 256, 4><<<cdiv(kE1, 64), TPB, 0, stream>>>(
        x, ei1, kE1, ea1, We1_l, be1_l, bufA);

    // ---- encoder spatial 2: h1[16] -> h2[32]  (h2 = bufB)
    upsample_kernel<16, 32, 8><<<cdiv((long)kN1 * 32, 2048), TPB, 0, stream>>>(
        bufA, kN1, We2_u, be2_u, bufB);
    spatial_edge_kernel<16, 3, 32, 256, 4><<<cdiv(kE1, 32), TPB, 0, stream>>>(
        bufA, ei1, kE1, ea1, We2_l, be2_l, bufB);

    // ---- encoder spatial 3: h2[32] -> h3[64]  (h3 = bufA)
    upsample_kernel<32, 64, 8><<<cdiv((long)kN1 * 64, 2048), TPB, 0, stream>>>(
        bufB, kN1, We3_u, be3_u, bufA);
    spatial_edge_kernel<32, 3, 64, 256, 8><<<cdiv(kE1, 32), TPB, 0, stream>>>(
        bufB, ei1, kE1, ea1, We3_l, be3_l, bufA);

    // ---- encoder temporal (dim 64): s1 = bufB, cnt1 = bufC, z in-place bufB
    hipMemsetAsync(bufB, 0, (size_t)kN1 * 64 * sizeof(float), stream);
    hipMemsetAsync(bufC, 0, (size_t)kN1 * sizeof(float), stream);
    temporal_gemm_kernel<<<kN1 / 128, 256, 0, stream>>>(
        bufA, tei1, kN1, Wt1, bt1, bufB, bufC);
    temporal_combine64_kernel<<<cdiv((long)kN1 * 64, TPB), TPB, 0, stream>>>(
        bufB, bufC, bufA, bufB, kN1);

    // ---- transform GEMM: z(bufB [65536,384] f32) @ W_tr^T -> tanh -> zt bf16
    {
        dim3 grid(kN / 128, kM / 128);
        gemm_mfma_tanh_kernel<<<grid, 256, 0, stream>>>(bufB, W_tr, b_tr, zt);
    }

    // ---- decoder spatial 1: x2[66] (virtual) -> d1[32]  (d1 = bufB)
    dec1_upsample_kernel<8><<<cdiv((long)kN2 * 32, 2048), TPB, 0, stream>>>(
        zt, lower, upper, Wd1_u, bd1_u, bufB, kN2);
    dec1_gemm_kernel<<<kE2 / 128, 256, 0, stream>>>(
        zt, lower, upper, ei2, kE2, ea2, Wd1_l, bd1_l, bufB);

    // ---- decoder spatial 2: d1[32] -> d2[16]  (d2 = bufA as f32)
    float* d2 = (float*)bufA;
    upsample_kernel<32, 16, 8><<<cdiv((long)kN2 * 16, 2048), TPB, 0, stream>>>(
        bufB, kN2, Wd2_u, bd2_u, d2);
    spatial_edge_kernel<32, 6, 16, 256, 4><<<cdiv(kE2, 64), TPB, 0, stream>>>(
        bufB, ei2, kE2, ea2, Wd2_l, bd2_l, d2);

    // ---- decoder spatial 3: d2[16] -> d3[1]  (d3 = bufB)
    float* d3 = bufB;
    upsample_kernel<16, 1, 8><<<cdiv(kN2, 2048), TPB, 0, stream>>>(
        d2, kN2, Wd3_u, bd3_u, d3);
    spatial_edge_kernel<16, 6, 1, 256, 1><<<cdiv(kE2, 256), TPB, 0, stream>>>(
        d2, ei2, kE2, ea2, Wd3_l, bd3_l, d3);

    // ---- decoder temporal (dim 1) + final affine
    hipMemsetAsync(bufC, 0, (size_t)2 * kN2 * sizeof(float), stream);
    temporal_edge1_kernel<<<cdiv(kN2, TPB), TPB, 0, stream>>>(
        d3, tei2, kN2, Wt2, bt2, bufC, bufC + kN2);
    final_kernel<<<cdiv(kN2, TPB), TPB, 0, stream>>>(
        bufC, bufC + kN2, d3, lower, upper, (float*)d_out, kN2);
}

// Round 7
// 1404.883 us; speedup vs baseline: 3.4573x; 1.1159x over previous
//
#include <hip/hip_runtime.h>
#include <hip/hip_bf16.h>

// ---------------------------------------------------------------------------
// ArmNet forward. Round 7: enc2/enc3/dec2 spatial edge-MLPs converted to the
// fused gather -> bf16 MFMA -> scatter GEMM pattern validated in round 6
// (temporal64 + dec1). enc1 (Z=15) and dec3 (OUT=1) stay as MLPs.
// ---------------------------------------------------------------------------

constexpr int kN1 = 393216;   // encoder nodes
constexpr int kE1 = 327680;   // encoder edges
constexpr int kN2 = 917504;   // decoder nodes
constexpr int kE2 = 851968;   // decoder edges
constexpr int kM  = 65536;    // B*PERIOD (transform GEMM rows)
constexpr int kK  = 384;      // transform K
constexpr int kN  = 896;      // transform N (14*64)

typedef __attribute__((ext_vector_type(8))) short bf16x8;
typedef __attribute__((ext_vector_type(4))) float f32x4;

__device__ inline float2 bf2_unpack(unsigned u) {
    union { unsigned i; float f; } a, b;
    a.i = u << 16;           // element 2j   (low half)
    b.i = u & 0xffff0000u;   // element 2j+1 (high half)
    return make_float2(a.f, b.f);
}

__device__ inline ushort f2bf(float f) {   // RNE f32 -> bf16 (finite inputs)
    union { float f; unsigned u; } x; x.f = f;
    unsigned r = x.u + 0x7fffu + ((x.u >> 16) & 1u);
    return (ushort)(r >> 16);
}

__device__ inline void pack8(ushort* d, float4 u, float4 v) {
    bf16x8 p;
    p[0] = (short)f2bf(u.x); p[1] = (short)f2bf(u.y);
    p[2] = (short)f2bf(u.z); p[3] = (short)f2bf(u.w);
    p[4] = (short)f2bf(v.x); p[5] = (short)f2bf(v.y);
    p[6] = (short)f2bf(v.z); p[7] = (short)f2bf(v.w);
    *(bf16x8*)d = p;
}

// ---------------- spatial edge MLP (small layers: enc1, dec3) --------------
template<int IN, int EA, int OUT, int TPB, int ITER>
__global__ __launch_bounds__(TPB)
void spatial_edge_kernel(const float* __restrict__ x,
                         const int* __restrict__ ei, int E,
                         const float* __restrict__ ea,
                         const float* __restrict__ Wl,
                         const float* __restrict__ bl,
                         float* __restrict__ out)
{
    constexpr int Z  = 2 * IN + EA;
    constexpr int Zp = (Z % 2 == 0) ? Z + 1 : Z;   // odd stride: conflict-free
    constexpr int EPB = TPB / OUT;
    static_assert(TPB % OUT == 0, "TPB % OUT");
    __shared__ float sW[OUT * Zp];
    __shared__ float sB[OUT];
    for (int i = threadIdx.x; i < OUT * Z; i += TPB)
        sW[(i / Z) * Zp + (i % Z)] = Wl[i];
    for (int i = threadIdx.x; i < OUT; i += TPB) sB[i] = bl[i];
    __syncthreads();

    const int le = threadIdx.x / OUT;
    const int c  = threadIdx.x % OUT;
    const float* __restrict__ w = &sW[c * Zp];
    const int base = blockIdx.x * EPB * ITER;

    #pragma unroll 1
    for (int it = 0; it < ITER; ++it) {
        const int e = base + it * EPB + le;
        if (e >= E) break;
        const int src = ei[e];
        const int dst = ei[E + e];
        float acc = sB[c];
        if constexpr (IN % 4 == 0) {
            const float4* __restrict__ xd4 = (const float4*)&x[(long)dst * IN];
            const float4* __restrict__ xs4 = (const float4*)&x[(long)src * IN];
            #pragma unroll
            for (int q = 0; q < IN / 4; ++q) {
                const float4 v = xd4[q];
                acc = fmaf(w[4*q+0], v.x, acc); acc = fmaf(w[4*q+1], v.y, acc);
                acc = fmaf(w[4*q+2], v.z, acc); acc = fmaf(w[4*q+3], v.w, acc);
            }
            #pragma unroll
            for (int q = 0; q < IN / 4; ++q) {
                const float4 v = xs4[q];
                acc = fmaf(w[IN+4*q+0], v.x, acc); acc = fmaf(w[IN+4*q+1], v.y, acc);
                acc = fmaf(w[IN+4*q+2], v.z, acc); acc = fmaf(w[IN+4*q+3], v.w, acc);
            }
        } else {
            const float* __restrict__ xd = &x[(long)dst * IN];
            const float* __restrict__ xs = &x[(long)src * IN];
            #pragma unroll
            for (int j = 0; j < IN; ++j) acc = fmaf(w[j], xd[j], acc);
            #pragma unroll
            for (int j = 0; j < IN; ++j) acc = fmaf(w[IN + j], xs[j], acc);
        }
        const float* __restrict__ eav = &ea[(long)e * EA];
        #pragma unroll
        for (int j = 0; j < EA; ++j) acc = fmaf(w[2 * IN + j], eav[j], acc);
        acc = acc > 0.f ? acc : 0.01f * acc;     // leaky_relu(0.01)
        atomicAdd(&out[(long)dst * OUT + c], acc);
    }
}

// ---------------- spatial edge layer as fused gather-MFMA-scatter GEMM -----
// A row r = [x[dst] | x[src] | ea | 0-pad] (bf16), B = Wl[OUT][Z] zero-padded.
// m = leaky_relu(A B^T + bl); out[dst] += m  (out pre-filled with residual).
template<int IN, int EA, int OUT, int KSTEPS>
__global__ __launch_bounds__(256)
void spatial_gemm_kernel(const float* __restrict__ x,
                         const int* __restrict__ ei, int E,
                         const float* __restrict__ ea,
                         const float* __restrict__ Wl,
                         const float* __restrict__ bl,
                         float* __restrict__ out)
{
    constexpr int Z    = 2 * IN + EA;
    constexpr int KPAD = KSTEPS * 32;
    static_assert(Z <= KPAD, "K pad");
    static_assert(IN % 8 == 0, "IN vec");
    constexpr int LDA = KPAD + 8;      // multiple of 8 ushorts (16B aligned rows)
    constexpr int MT  = 128;
    constexpr int NF  = OUT / 16;
    __shared__ ushort sA[MT * LDA];
    __shared__ ushort sB[OUT * LDA];
    __shared__ float  sBias[OUT];
    __shared__ int    sDst[MT];

    const int tid = threadIdx.x;
    const int e0  = blockIdx.x * MT;

    // stage B (zero-padded k)
    for (int i = tid; i < OUT * KPAD; i += 256) {
        const int ch = i / KPAD, j = i % KPAD;
        sB[ch * LDA + j] = (j < Z) ? f2bf(Wl[ch * Z + j]) : (ushort)0;
    }
    if (tid < OUT) sBias[tid] = bl[tid];

    // stage A: 2 threads per edge row (sh=0: dst half, sh=1: src half + ea + pad)
    {
        const int r  = tid >> 1, sh = tid & 1;
        const int e  = e0 + r;
        const int node = sh ? ei[e] : ei[E + e];
        const float4* __restrict__ xr = (const float4*)&x[(long)node * IN];
        ushort* d = &sA[r * LDA + sh * IN];
        #pragma unroll
        for (int q = 0; q < IN / 4; q += 2)
            pack8(d + q * 4, xr[q], xr[q + 1]);
        if (sh == 0) {
            sDst[r] = node;
        } else {
            const float* __restrict__ eav = &ea[(long)e * EA];
            #pragma unroll
            for (int j = 0; j < EA; ++j) d[IN + j] = f2bf(eav[j]);  // abs 2*IN+j
            #pragma unroll
            for (int j = Z; j < KPAD; ++j) sA[r * LDA + j] = 0;
        }
    }
    __syncthreads();

    const int lane = tid & 63, wid = tid >> 6;
    const int g = lane >> 4, rsel = lane & 15;
    f32x4 acc[2][NF] = {};
    #pragma unroll
    for (int ks = 0; ks < KSTEPS; ++ks) {
        bf16x8 a_[2], b_[NF];
        #pragma unroll
        for (int m = 0; m < 2; ++m)
            a_[m] = *(const bf16x8*)&sA[(wid*32 + m*16 + rsel) * LDA + ks*32 + g*8];
        #pragma unroll
        for (int n = 0; n < NF; ++n)
            b_[n] = *(const bf16x8*)&sB[(n*16 + rsel) * LDA + ks*32 + g*8];
        #pragma unroll
        for (int m = 0; m < 2; ++m)
            #pragma unroll
            for (int n = 0; n < NF; ++n)
                acc[m][n] = __builtin_amdgcn_mfma_f32_16x16x32_bf16(
                    a_[m], b_[n], acc[m][n], 0, 0, 0);
    }

    // epilogue: row = wid*32 + m*16 + g*4 + rr ; col = n*16 + rsel
    #pragma unroll
    for (int m = 0; m < 2; ++m) {
        #pragma unroll
        for (int rr = 0; rr < 4; ++rr) {
            const int row = wid*32 + m*16 + g*4 + rr;
            const long dst = sDst[row];
            #pragma unroll
            for (int n = 0; n < NF; ++n) {
                const int col = n*16 + rsel;
                float v = acc[m][n][rr] + sBias[col];
                v = v > 0.f ? v : 0.01f * v;
                atomicAdd(&out[dst * OUT + col], v);
            }
        }
    }
}

// ---------------- generic upsample (residual linear) -----------------------
template<int IN, int OUT, int ITER>
__global__ __launch_bounds__(256)
void upsample_kernel(const float* __restrict__ x, int N,
                     const float* __restrict__ Wu,
                     const float* __restrict__ bu,
                     float* __restrict__ out)
{
    constexpr int INp = (IN % 2 == 0) ? IN + 1 : IN;
    __shared__ float sW[OUT * INp];
    __shared__ float sB[OUT];
    for (int i = threadIdx.x; i < OUT * IN; i += 256)
        sW[(i / IN) * INp + (i % IN)] = Wu[i];
    for (int i = threadIdx.x; i < OUT; i += 256) sB[i] = bu[i];
    __syncthreads();

    const int total = N * OUT;
    #pragma unroll 1
    for (int it = 0; it < ITER; ++it) {
        const int idx = (blockIdx.x * ITER + it) * 256 + threadIdx.x;
        if (idx >= total) break;
        const int n = idx / OUT, c = idx % OUT;
        const float* __restrict__ w = &sW[c * INp];
        float acc = sB[c];
        if constexpr (IN % 4 == 0) {
            const float4* __restrict__ xv4 = (const float4*)&x[(long)n * IN];
            #pragma unroll
            for (int q = 0; q < IN / 4; ++q) {
                const float4 v = xv4[q];
                acc = fmaf(w[4*q+0], v.x, acc); acc = fmaf(w[4*q+1], v.y, acc);
                acc = fmaf(w[4*q+2], v.z, acc); acc = fmaf(w[4*q+3], v.w, acc);
            }
        } else {
            const float* __restrict__ xv = &x[(long)n * IN];
            #pragma unroll
            for (int j = 0; j < IN; ++j) acc = fmaf(w[j], xv[j], acc);
        }
        out[idx] = acc;
    }
}

template<int ITER>
__global__ __launch_bounds__(256)
void dec1_upsample_kernel(const __hip_bfloat16* __restrict__ zt,
                          const float* __restrict__ lo,
                          const float* __restrict__ up,
                          const float* __restrict__ Wu,  // [32, 66]
                          const float* __restrict__ bu,
                          float* __restrict__ out, int N)
{
    constexpr int IN = 66, INp = 67, OUT = 32;
    __shared__ float sW[OUT * INp];
    __shared__ float sB[OUT];
    for (int i = threadIdx.x; i < OUT * IN; i += 256)
        sW[(i / IN) * INp + (i % IN)] = Wu[i];
    if (threadIdx.x < OUT) sB[threadIdx.x] = bu[threadIdx.x];
    __syncthreads();

    const int total = N * OUT;
    #pragma unroll 1
    for (int it = 0; it < ITER; ++it) {
        const int idx = (blockIdx.x * ITER + it) * 256 + threadIdx.x;
        if (idx >= total) break;
        const int n = idx >> 5, c = idx & 31;
        const float* __restrict__ w = &sW[c * INp];
        const uint4* __restrict__ zn4 = (const uint4*)&zt[(long)n * 64];
        float acc = sB[c];
        #pragma unroll
        for (int q = 0; q < 8; ++q) {
            const uint4 u = zn4[q];
            float2 v;
            v = bf2_unpack(u.x); acc = fmaf(w[8*q+0], v.x, acc); acc = fmaf(w[8*q+1], v.y, acc);
            v = bf2_unpack(u.y); acc = fmaf(w[8*q+2], v.x, acc); acc = fmaf(w[8*q+3], v.y, acc);
            v = bf2_unpack(u.z); acc = fmaf(w[8*q+4], v.x, acc); acc = fmaf(w[8*q+5], v.y, acc);
            v = bf2_unpack(u.w); acc = fmaf(w[8*q+6], v.x, acc); acc = fmaf(w[8*q+7], v.y, acc);
        }
        acc = fmaf(w[64], lo[n], acc);
        acc = fmaf(w[65], up[n], acc);
        out[idx] = acc;
    }
}

// ---------------- temporal (dim 64) as fused gather-MFMA-scatter GEMM ------
__global__ __launch_bounds__(256)
void temporal_gemm_kernel(const float* __restrict__ x,
                          const int* __restrict__ ei, int E,
                          const float* __restrict__ Wt,  // [64,128]
                          const float* __restrict__ bt,
                          float* __restrict__ s, float* __restrict__ cnt)
{
    constexpr int MT = 128, LDA = 136, LDB = 136;
    __shared__ ushort sA[MT * LDA];     // 34816 B
    __shared__ ushort sB[64 * LDB];     // 17408 B
    __shared__ float  sBias[64];
    __shared__ int    sDst[MT];

    const int tid = threadIdx.x;
    const int e0  = blockIdx.x * MT;

    // stage B (Wt) + bias
    for (int i = tid; i < 64 * 32; i += 256) {
        const int ch = i >> 5, q = i & 31;
        const float4 v = *(const float4*)&Wt[ch * 128 + q * 4];
        ushort* d = &sB[ch * LDB + q * 4];
        d[0] = f2bf(v.x); d[1] = f2bf(v.y); d[2] = f2bf(v.z); d[3] = f2bf(v.w);
    }
    if (tid < 64) sBias[tid] = bt[tid];

    // stage A: 2 threads per edge row (sh=0: dst half, sh=1: src half)
    {
        const int r  = tid >> 1, sh = tid & 1;
        const int e  = e0 + r;
        const int node = sh ? ei[e] : ei[E + e];
        const float4* __restrict__ xr = (const float4*)&x[(long)node * 64];
        ushort* d = &sA[r * LDA + sh * 64];
        #pragma unroll
        for (int q = 0; q < 16; q += 2)
            pack8(d + q * 4, xr[q], xr[q + 1]);
        if (sh == 0) {
            sDst[r] = node;
            atomicAdd(&cnt[node], 1.f);
        }
    }
    __syncthreads();

    // MFMA: wave wid owns edge rows [wid*32, wid*32+32)
    const int lane = tid & 63, wid = tid >> 6;
    const int g = lane >> 4, rsel = lane & 15;
    f32x4 acc[2][4] = {};
    #pragma unroll
    for (int ks = 0; ks < 4; ++ks) {
        bf16x8 a_[2], b_[4];
        #pragma unroll
        for (int m = 0; m < 2; ++m)
            a_[m] = *(const bf16x8*)&sA[(wid*32 + m*16 + rsel) * LDA + ks*32 + g*8];
        #pragma unroll
        for (int n = 0; n < 4; ++n)
            b_[n] = *(const bf16x8*)&sB[(n*16 + rsel) * LDB + ks*32 + g*8];
        #pragma unroll
        for (int m = 0; m < 2; ++m)
            #pragma unroll
            for (int n = 0; n < 4; ++n)
                acc[m][n] = __builtin_amdgcn_mfma_f32_16x16x32_bf16(
                    a_[m], b_[n], acc[m][n], 0, 0, 0);
    }

    #pragma unroll
    for (int m = 0; m < 2; ++m) {
        #pragma unroll
        for (int rr = 0; rr < 4; ++rr) {
            const int row = wid*32 + m*16 + g*4 + rr;
            const long dst = sDst[row];
            #pragma unroll
            for (int n = 0; n < 4; ++n) {
                const int col = n*16 + rsel;
                const float v = fmaxf(acc[m][n][rr] + sBias[col], 0.f);
                atomicAdd(&s[dst * 64 + col], v);
            }
        }
    }
}

// ---------------- decoder layer-1 as fused gather-MFMA-scatter GEMM --------
__global__ __launch_bounds__(256)
void dec1_gemm_kernel(const __hip_bfloat16* __restrict__ zt,
                      const float* __restrict__ lo, const float* __restrict__ up,
                      const int* __restrict__ ei, int E,
                      const float* __restrict__ ea,   // [E,6]
                      const float* __restrict__ Wl,   // [32,138]
                      const float* __restrict__ bl,
                      float* __restrict__ out)        // [N2,32]
{
    constexpr int MT = 128, LDA = 168, LDB = 168;
    __shared__ ushort sA[MT * LDA];     // 43008 B
    __shared__ ushort sB[32 * LDB];     // 10752 B
    __shared__ float  sBias[32];
    __shared__ int    sDst[MT];

    const int tid = threadIdx.x;
    const int e0  = blockIdx.x * MT;

    for (int i = tid; i < 32 * 160; i += 256) {
        const int ch = i / 160, j = i % 160;
        sB[ch * LDB + j] = (j < 138) ? f2bf(Wl[ch * 138 + j]) : (ushort)0;
    }
    if (tid < 32) sBias[tid] = bl[tid];

    {
        const int r  = tid >> 1, sh = tid & 1;
        const int e  = e0 + r;
        const int node = sh ? ei[e] : ei[E + e];
        ushort* d = &sA[r * LDA + sh * 66];
        uint* d32 = (uint*)d;                     // 4B-aligned
        const uint4* __restrict__ zr = (const uint4*)&zt[(long)node * 64];
        #pragma unroll
        for (int q = 0; q < 8; ++q) {
            const uint4 u = zr[q];
            d32[4*q+0] = u.x; d32[4*q+1] = u.y; d32[4*q+2] = u.z; d32[4*q+3] = u.w;
        }
        d[64] = f2bf(lo[node]);
        d[65] = f2bf(up[node]);
        if (sh) {
            const float* __restrict__ eav = &ea[(long)e * 6];
            #pragma unroll
            for (int j = 0; j < 6; ++j) d[66 + j] = f2bf(eav[j]);
            #pragma unroll
            for (int j = 72; j < 94; ++j) d[j] = 0;   // k 138..159
        } else {
            sDst[r] = node;
        }
    }
    __syncthreads();

    const int lane = tid & 63, wid = tid >> 6;
    const int g = lane >> 4, rsel = lane & 15;
    f32x4 acc[2][2] = {};
    #pragma unroll
    for (int ks = 0; ks < 5; ++ks) {
        bf16x8 a_[2], b_[2];
        #pragma unroll
        for (int m = 0; m < 2; ++m)
            a_[m] = *(const bf16x8*)&sA[(wid*32 + m*16 + rsel) * LDA + ks*32 + g*8];
        #pragma unroll
        for (int n = 0; n < 2; ++n)
            b_[n] = *(const bf16x8*)&sB[(n*16 + rsel) * LDB + ks*32 + g*8];
        #pragma unroll
        for (int m = 0; m < 2; ++m)
            #pragma unroll
            for (int n = 0; n < 2; ++n)
                acc[m][n] = __builtin_amdgcn_mfma_f32_16x16x32_bf16(
                    a_[m], b_[n], acc[m][n], 0, 0, 0);
    }

    #pragma unroll
    for (int m = 0; m < 2; ++m) {
        #pragma unroll
        for (int rr = 0; rr < 4; ++rr) {
            const int row = wid*32 + m*16 + g*4 + rr;
            const long dst = sDst[row];
            #pragma unroll
            for (int n = 0; n < 2; ++n) {
                const int col = n*16 + rsel;
                float v = acc[m][n][rr] + sBias[col];
                v = v > 0.f ? v : 0.01f * v;
                atomicAdd(&out[dst * 32 + col], v);
            }
        }
    }
}

// ---------------- temporal combine / dim-1 temporal ------------------------
__global__ void temporal_combine64_kernel(const float* __restrict__ s,
                                          const float* __restrict__ cnt,
                                          const float* __restrict__ x,
                                          float* __restrict__ z, int N)
{
    int idx = blockIdx.x * blockDim.x + threadIdx.x;
    if (idx >= N * 64) return;
    const int n = idx >> 6;
    z[idx] = s[idx] / fmaxf(cnt[n], 1.f) + x[idx];
}

__global__ void temporal_edge1_kernel(const float* __restrict__ x,
                                      const int* __restrict__ ei, int E,
                                      const float* __restrict__ Wt,
                                      const float* __restrict__ bt,
                                      float* __restrict__ s, float* __restrict__ cnt)
{
    int e = blockIdx.x * blockDim.x + threadIdx.x;
    if (e >= E) return;
    const int src = ei[e];
    const int dst = ei[E + e];
    float m = Wt[0] * x[dst] + Wt[1] * x[src] + bt[0];
    m = fmaxf(m, 0.f);
    atomicAdd(&s[dst], m);
    atomicAdd(&cnt[dst], 1.f);
}

// ---------------- transform GEMM (bf16 MFMA, cast on stage) ----------------
__global__ __launch_bounds__(256)
void gemm_mfma_tanh_kernel(const float* __restrict__ A,
                           const float* __restrict__ W,
                           const float* __restrict__ bias,
                           __hip_bfloat16* __restrict__ out)
{
    constexpr int BM = 128, LDP = 40;   // ushort pitch: 80B rows, 2-way banks
    __shared__ ushort sA[BM * LDP];
    __shared__ ushort sB[BM * LDP];
    const int tid  = threadIdx.x;
    const int lane = tid & 63;
    const int wid  = tid >> 6;
    const int wr = wid >> 1, wc = wid & 1;
    const long bm = (long)blockIdx.y * BM;
    const long bn = (long)blockIdx.x * BM;

    const int sr = tid >> 1;      // 0..127: staged tile row
    const int sh = tid & 1;       // 0/1: which 16-element k-half
    const float* __restrict__ gA = &A[(bm + sr) * kK + sh * 16];
    const float* __restrict__ gB = &W[(bn + sr) * kK + sh * 16];
    ushort* dA = &sA[sr * LDP + sh * 16];
    ushort* dB = &sB[sr * LDP + sh * 16];

    f32x4 acc[4][4] = {};
    const int g    = lane >> 4;   // k-group (8 bf16 each)
    const int rsel = lane & 15;

    for (int k0 = 0; k0 < kK; k0 += 32) {
        const float4 a0 = *(const float4*)(gA + k0 + 0);
        const float4 a1 = *(const float4*)(gA + k0 + 4);
        const float4 a2 = *(const float4*)(gA + k0 + 8);
        const float4 a3 = *(const float4*)(gA + k0 + 12);
        const float4 b0 = *(const float4*)(gB + k0 + 0);
        const float4 b1 = *(const float4*)(gB + k0 + 4);
        const float4 b2 = *(const float4*)(gB + k0 + 8);
        const float4 b3 = *(const float4*)(gB + k0 + 12);
        __syncthreads();                      // previous tile fully consumed
        pack8(dA, a0, a1); pack8(dA + 8, a2, a3);
        pack8(dB, b0, b1); pack8(dB + 8, b2, b3);
        __syncthreads();

        bf16x8 af[4], bfm[4];
        #pragma unroll
        for (int m = 0; m < 4; ++m)
            af[m] = *(const bf16x8*)&sA[(wr * 64 + m * 16 + rsel) * LDP + g * 8];
        #pragma unroll
        for (int n = 0; n < 4; ++n)
            bfm[n] = *(const bf16x8*)&sB[(wc * 64 + n * 16 + rsel) * LDP + g * 8];
        #pragma unroll
        for (int m = 0; m < 4; ++m)
            #pragma unroll
            for (int n = 0; n < 4; ++n)
                acc[m][n] = __builtin_amdgcn_mfma_f32_16x16x32_bf16(
                    af[m], bfm[n], acc[m][n], 0, 0, 0);
    }

    // epilogue: D frag col = lane&15, row = (lane>>4)*4 + reg
    const long colb = bn + wc * 64 + (lane & 15);
    const long rowb = bm + wr * 64 + (lane >> 4) * 4;
    #pragma unroll
    for (int n = 0; n < 4; ++n) {
        const long col = colb + n * 16;
        const float bs = bias[col];
        #pragma unroll
        for (int m = 0; m < 4; ++m) {
            #pragma unroll
            for (int r = 0; r < 4; ++r) {
                const float v = tanhf(acc[m][n][r] + bs);
                out[(rowb + m * 16 + r) * kN + col] = __float2bfloat16(v);
            }
        }
    }
}

// ---------------- final: tanh(temporal) -> affine to joint range -----------
__global__ void final_kernel(const float* __restrict__ s,
                             const float* __restrict__ cnt,
                             const float* __restrict__ d3,
                             const float* __restrict__ lo,
                             const float* __restrict__ up,
                             float* __restrict__ out, int N)
{
    int i = blockIdx.x * blockDim.x + threadIdx.x;
    if (i >= N) return;
    const float t = s[i] / fmaxf(cnt[i], 1.f) + d3[i];
    const float o = tanhf(t);
    out[i] = lo[i] + (up[i] - lo[i]) * (o + 1.f) * 0.5f;
}

// ---------------------------------------------------------------------------
extern "C" void kernel_launch(void* const* d_in, const int* in_sizes, int n_in,
                              void* d_out, int out_size, void* d_ws, size_t ws_size,
                              hipStream_t stream)
{
    const float* x     = (const float*)d_in[0];
    const int*   ei1   = (const int*)  d_in[1];
    const float* ea1   = (const float*)d_in[2];
    const int*   tei1  = (const int*)  d_in[3];
    const float* lower = (const float*)d_in[4];
    const float* upper = (const float*)d_in[5];
    const int*   ei2   = (const int*)  d_in[6];
    const float* ea2   = (const float*)d_in[7];
    const int*   tei2  = (const int*)  d_in[8];
    const float* We1_l = (const float*)d_in[9];  const float* be1_l = (const float*)d_in[10];
    const float* We1_u = (const float*)d_in[11]; const float* be1_u = (const float*)d_in[12];
    const float* We2_l = (const float*)d_in[13]; const float* be2_l = (const float*)d_in[14];
    const float* We2_u = (const float*)d_in[15]; const float* be2_u = (const float*)d_in[16];
    const float* We3_l = (const float*)d_in[17]; const float* be3_l = (const float*)d_in[18];
    const float* We3_u = (const float*)d_in[19]; const float* be3_u = (const float*)d_in[20];
    const float* Wt1   = (const float*)d_in[21]; const float* bt1   = (const float*)d_in[22];
    const float* W_tr  = (const float*)d_in[23]; const float* b_tr  = (const float*)d_in[24];
    const float* Wd1_l = (const float*)d_in[25]; const float* bd1_l = (const float*)d_in[26];
    const float* Wd1_u = (const float*)d_in[27]; const float* bd1_u = (const float*)d_in[28];
    const float* Wd2_l = (const float*)d_in[29]; const float* bd2_l = (const float*)d_in[30];
    const float* Wd2_u = (const float*)d_in[31]; const float* bd2_u = (const float*)d_in[32];
    const float* Wd3_l = (const float*)d_in[33]; const float* bd3_l = (const float*)d_in[34];
    const float* Wd3_u = (const float*)d_in[35]; const float* bd3_u = (const float*)d_in[36];
    const float* Wt2   = (const float*)d_in[37]; const float* bt2   = (const float*)d_in[38];

    // workspace layout (bytes):
    //   bufA: 117,440,512   (holds h1/h3/zt(bf16)/d2)
    //   bufB: 117,440,512   (holds h2/s1/z/d1/d3)
    //   bufC:   7,340,032   (holds cnt1 | s2+cnt2)
    char* ws = (char*)d_ws;
    float* bufA = (float*)ws;
    float* bufB = (float*)(ws + 117440512);
    float* bufC = (float*)(ws + 234881024);
    __hip_bfloat16* zt = (__hip_bfloat16*)bufA;

    const int TPB = 256;
    auto cdiv = [](long a, long b) { return (int)((a + b - 1) / b); };

    // ---- encoder spatial 1: x[6] -> h1[16]  (h1 = bufA)
    upsample_kernel<6, 16, 8><<<cdiv((long)kN1 * 16, 2048), TPB, 0, stream>>>(
        x, kN1, We1_u, be1_u, bufA);
    spatial_edge_kernel<6, 3, 16, 256, 4><<<cdiv(kE1, 64), TPB, 0, stream>>>(
        x, ei1, kE1, ea1, We1_l, be1_l, bufA);

    // ---- encoder spatial 2: h1[16] -> h2[32]  (h2 = bufB)
    upsample_kernel<16, 32, 8><<<cdiv((long)kN1 * 32, 2048), TPB, 0, stream>>>(
        bufA, kN1, We2_u, be2_u, bufB);
    spatial_gemm_kernel<16, 3, 32, 2><<<kE1 / 128, TPB, 0, stream>>>(
        bufA, ei1, kE1, ea1, We2_l, be2_l, bufB);

    // ---- encoder spatial 3: h2[32] -> h3[64]  (h3 = bufA)
    upsample_kernel<32, 64, 8><<<cdiv((long)kN1 * 64, 2048), TPB, 0, stream>>>(
        bufB, kN1, We3_u, be3_u, bufA);
    spatial_gemm_kernel<32, 3, 64, 3><<<kE1 / 128, TPB, 0, stream>>>(
        bufB, ei1, kE1, ea1, We3_l, be3_l, bufA);

    // ---- encoder temporal (dim 64): s1 = bufB, cnt1 = bufC, z in-place bufB
    hipMemsetAsync(bufB, 0, (size_t)kN1 * 64 * sizeof(float), stream);
    hipMemsetAsync(bufC, 0, (size_t)kN1 * sizeof(float), stream);
    temporal_gemm_kernel<<<kN1 / 128, 256, 0, stream>>>(
        bufA, tei1, kN1, Wt1, bt1, bufB, bufC);
    temporal_combine64_kernel<<<cdiv((long)kN1 * 64, TPB), TPB, 0, stream>>>(
        bufB, bufC, bufA, bufB, kN1);

    // ---- transform GEMM: z(bufB [65536,384] f32) @ W_tr^T -> tanh -> zt bf16
    {
        dim3 grid(kN / 128, kM / 128);
        gemm_mfma_tanh_kernel<<<grid, 256, 0, stream>>>(bufB, W_tr, b_tr, zt);
    }

    // ---- decoder spatial 1: x2[66] (virtual) -> d1[32]  (d1 = bufB)
    dec1_upsample_kernel<8><<<cdiv((long)kN2 * 32, 2048), TPB, 0, stream>>>(
        zt, lower, upper, Wd1_u, bd1_u, bufB, kN2);
    dec1_gemm_kernel<<<kE2 / 128, 256, 0, stream>>>(
        zt, lower, upper, ei2, kE2, ea2, Wd1_l, bd1_l, bufB);

    // ---- decoder spatial 2: d1[32] -> d2[16]  (d2 = bufA as f32)
    float* d2 = (float*)bufA;
    upsample_kernel<32, 16, 8><<<cdiv((long)kN2 * 16, 2048), TPB, 0, stream>>>(
        bufB, kN2, Wd2_u, bd2_u, d2);
    spatial_gemm_kernel<32, 6, 16, 3><<<kE2 / 128, TPB, 0, stream>>>(
        bufB, ei2, kE2, ea2, Wd2_l, bd2_l, d2);

    // ---- decoder spatial 3: d2[16] -> d3[1]  (d3 = bufB)
    float* d3 = bufB;
    upsample_kernel<16, 1, 8><<<cdiv(kN2, 2048), TPB, 0, stream>>>(
        d2, kN2, Wd3_u, bd3_u, d3);
    spatial_edge_kernel<16, 6, 1, 256, 1><<<cdiv(kE2, 256), TPB, 0, stream>>>(
        d2, ei2, kE2, ea2, Wd3_l, bd3_l, d3);

    // ---- decoder temporal (dim 1) + final affine
    hipMemsetAsync(bufC, 0, (size_t)2 * kN2 * sizeof(float), stream);
    temporal_edge1_kernel<<<cdiv(kN2, TPB), TPB, 0, stream>>>(
        d3, tei2, kN2, Wt2, bt2, bufC, bufC + kN2);
    final_kernel<<<cdiv(kN2, TPB), TPB, 0, stream>>>(
        bufC, bufC + kN2, d3, lower, upper, (float*)d_out, kN2);
}